// Round 5
// baseline (617.059 us; speedup 1.0000x reference)
//
#include <hip/hip_runtime.h>
#include <hip/hip_bf16.h>
#include <math.h>

// GRUCell with adaptive-graph GCN on MI355X (gfx950).
// B=64, N=2048, Din=2, H=64, D=16, C=66, O=64.
// R13: k_gemm is LDS-PORT-BOUND (144KB/CU-iter at ~128B/cy ≈ measured 1000cy
//      period; MfmaUtil 27% = 310/1125 — explains why R10-R12 pipeline changes
//      were all flat). Fix: X operand fragments are per-lane 16B-contiguous in
//      XT -> load them DIRECTLY global->register (no Xt LDS at all, register
//      double-buffer, compiler auto-inserts counted vmcnt for the reg loads).
//      A stays global_load_lds-staged (2x reuse), 2 bufs dist-1, uniform
//      manual vmcnt(4) (forces only A(i); X waits are compiler-counted).
//      LDS 49KB->16KB, LDS traffic halved. T1/T2(A-side)/setprio retained.

typedef __attribute__((ext_vector_type(4))) float f4;
typedef __attribute__((ext_vector_type(8))) short s8;  // 8 bf16 in 4 VGPRs (MFMA A/B frag)

#define B_   64
#define N_   2048
#define DIN  2
#define H_   64
#define D_   16
#define C_   66    // DIN + H
#define KI   132   // 2*C
#define KIP  160   // KI padded for K-loop (multiple of 32)
#define CB   4224  // B_*C_

#define GLD16(gp, lp) __builtin_amdgcn_global_load_lds((const __attribute__((address_space(1))) void*)(gp), (__attribute__((address_space(3))) void*)(lp), 16, 0, 0)

static __device__ __forceinline__ ushort f2bf(float v) {
  __hip_bfloat16 h = __float2bfloat16(v);
  return *(ushort*)&h;
}
static __device__ __forceinline__ float bf2f(ushort u) {
  __hip_bfloat16 h = *(__hip_bfloat16*)&u;
  return __bfloat162float(h);
}
static __device__ __forceinline__ uint packbf(float a, float b) {
  return ((uint)f2bf(b) << 16) | f2bf(a);
}

// ---------------------------------------------------------------- e = LN(node+time)*gamma+beta (fp32 + bf16 copies)
__global__ void k_e(const float* __restrict__ node, const float* __restrict__ timee,
                    const float* __restrict__ g0, const float* __restrict__ b0,
                    const float* __restrict__ g1, const float* __restrict__ b1,
                    const float* __restrict__ g2, const float* __restrict__ b2,
                    float* __restrict__ e, ushort* __restrict__ ebf) {
  int n = blockIdx.x * blockDim.x + threadIdx.x;
  if (n >= N_) return;
  float v[D_]; float m = 0.f;
  #pragma unroll
  for (int d = 0; d < D_; ++d) { v[d] = node[n * D_ + d] + timee[d]; m += v[d]; }
  m *= (1.0f / D_);
  float var = 0.f;
  #pragma unroll
  for (int d = 0; d < D_; ++d) { float t = v[d] - m; var += t * t; }
  var *= (1.0f / D_);
  float r = rsqrtf(var + 1e-12f);
  float y[D_];
  #pragma unroll
  for (int d = 0; d < D_; ++d) y[d] = (v[d] - m) * r;
  const float* gs[3] = {g0, g1, g2};
  const float* bs[3] = {b0, b1, b2};
  #pragma unroll
  for (int g = 0; g < 3; ++g) {
    #pragma unroll
    for (int d = 0; d < D_; d += 2) {
      float o0 = y[d] * gs[g][d] + bs[g][d];
      float o1 = y[d + 1] * gs[g][d + 1] + bs[g][d + 1];
      e[g * N_ * D_ + n * D_ + d] = o0;
      e[g * N_ * D_ + n * D_ + d + 1] = o1;
      *(uint*)&ebf[g * N_ * D_ + n * D_ + d] = packbf(o0, o1);
    }
  }
}

// ---------------------------------------------------------------- fused A_g = softmax(e_g e_g^T, axis=1), bf16
__global__ __launch_bounds__(256)
void k_attn(const ushort* __restrict__ ebf, __hip_bfloat16* __restrict__ A) {
  __shared__ __align__(16) ushort eb[N_ * D_];   // 64 KB
  __shared__ float red[4][16];
  const int t = threadIdx.x;
  const ushort* eg = ebf + (size_t)blockIdx.z * (N_ * D_);
  {
    const uint4* src = (const uint4*)eg;
    uint4* dst = (uint4*)eb;
    #pragma unroll
    for (int i = 0; i < 16; ++i) dst[i * 256 + t] = src[i * 256 + t];
  }
  __syncthreads();
  const int lane = t & 63, w = t >> 6;
  const int l15 = lane & 15, q = lane >> 4;
  const int r0 = blockIdx.x * 16;
  s8 rf = {0, 0, 0, 0, 0, 0, 0, 0};
  if (q < 2) rf = *(const s8*)&eb[(r0 + l15) * D_ + q * 8];
  const int c0 = w * 512;
  f4 acc[32];
  #pragma unroll
  for (int tl = 0; tl < 32; ++tl) {
    s8 cf = {0, 0, 0, 0, 0, 0, 0, 0};
    if (q < 2) cf = *(const s8*)&eb[(c0 + tl * 16 + l15) * D_ + q * 8];
    acc[tl] = __builtin_amdgcn_mfma_f32_16x16x32_bf16(cf, rf, (f4)0.0f, 0, 0, 0);
  }
  float m = acc[0][0];
  #pragma unroll
  for (int tl = 0; tl < 32; ++tl) {
    #pragma unroll
    for (int rg = 0; rg < 4; ++rg) m = fmaxf(m, acc[tl][rg]);
  }
  m = fmaxf(m, __shfl_xor(m, 16, 64));
  m = fmaxf(m, __shfl_xor(m, 32, 64));
  if (lane < 16) red[w][l15] = m;
  __syncthreads();
  const float gm = fmaxf(fmaxf(red[0][l15], red[1][l15]), fmaxf(red[2][l15], red[3][l15]));
  __syncthreads();
  float ps = 0.f;
  #pragma unroll
  for (int tl = 0; tl < 32; ++tl) {
    #pragma unroll
    for (int rg = 0; rg < 4; ++rg) {
      float v = __expf(acc[tl][rg] - gm);
      acc[tl][rg] = v;
      ps += v;
    }
  }
  ps += __shfl_xor(ps, 16, 64);
  ps += __shfl_xor(ps, 32, 64);
  if (lane < 16) red[w][l15] = ps;
  __syncthreads();
  const float inv = 1.0f / (red[0][l15] + red[1][l15] + red[2][l15] + red[3][l15]);
  ushort* Ar = (ushort*)A + (size_t)blockIdx.z * ((size_t)N_ * N_) +
               (size_t)(r0 + l15) * N_ + c0 + q * 4;
  #pragma unroll
  for (int tl = 0; tl < 32; ++tl) {
    uint2 pk;
    pk.x = packbf(acc[tl][0] * inv, acc[tl][1] * inv);
    pk.y = packbf(acc[tl][2] * inv, acc[tl][3] * inv);
    *(uint2*)&Ar[tl * 16] = pk;
  }
}

// ---------------------------------------------------------------- X^T[j=b*C+c][m] bf16 via LDS transpose
template <int MODE>  // 0: xs=[x,state]   1: cand=[x, z*state]
__global__ __launch_bounds__(256)
void k_buildX(const float* __restrict__ x, const float* __restrict__ state,
              const __hip_bfloat16* __restrict__ zbuf, __hip_bfloat16* __restrict__ XT) {
  constexpr int LDM = 72;
  __shared__ __align__(16) ushort T[C_ * LDM];
  const int t = threadIdx.x;
  const int m0 = blockIdx.x * 64, b = blockIdx.y;
  const int m = t >> 2, hq = t & 3;
  {
    const float* sp = state + ((size_t)b * N_ + m0 + m) * H_ + hq * 16;
    float sv[16];
    #pragma unroll
    for (int i = 0; i < 16; i += 4) {
      float4 v = *(const float4*)(sp + i);
      sv[i] = v.x; sv[i + 1] = v.y; sv[i + 2] = v.z; sv[i + 3] = v.w;
    }
    if (MODE) {
      const ushort* zp = (const ushort*)zbuf + ((size_t)b * N_ + m0 + m) * H_ + hq * 16;
      uint4 z0 = *(const uint4*)&zp[0], z1 = *(const uint4*)&zp[8];
      uint zw[8] = {z0.x, z0.y, z0.z, z0.w, z1.x, z1.y, z1.z, z1.w};
      #pragma unroll
      for (int i = 0; i < 8; ++i) {
        sv[2 * i]     *= bf2f((ushort)(zw[i] & 0xffffu));
        sv[2 * i + 1] *= bf2f((ushort)(zw[i] >> 16));
      }
    }
    #pragma unroll
    for (int i = 0; i < 16; ++i) T[(DIN + hq * 16 + i) * LDM + m] = f2bf(sv[i]);
    if (t < 64) {
      const float2 xv = *(const float2*)&x[((size_t)b * N_ + m0 + t) * DIN];
      T[0 * LDM + t] = f2bf(xv.x);
      T[1 * LDM + t] = f2bf(xv.y);
    }
  }
  __syncthreads();
  {
    int r = t >> 2, ch = t & 3;
    ushort* dst = (ushort*)XT + (size_t)(b * C_ + r) * N_ + m0 + ch * 16;
    *(uint4*)&dst[0] = *(uint4*)&T[r * LDM + ch * 16];
    *(uint4*)&dst[8] = *(uint4*)&T[r * LDM + ch * 16 + 8];
    if (t < 8) {
      r = 64 + (t >> 2);
      ushort* dst2 = (ushort*)XT + (size_t)(b * C_ + r) * N_ + m0 + ch * 16;
      *(uint4*)&dst2[0] = *(uint4*)&T[r * LDM + ch * 16];
      *(uint4*)&dst2[8] = *(uint4*)&T[r * LDM + ch * 16 + 8];
    }
  }
}

// ---------------------------------------------------------------- Y[r,j] = sum_m A[r,m] XT[j,m]
// R13: A-only LDS staging (2 bufs, dist-1, GLD16); X fragments loaded per-lane
// global->register (16B contiguous, 64B-line coalesced per quarter-row, L1
// dedups the wr-duplicate). LDS port traffic halved: 144->72 KB/CU-iter.
// Manual vmcnt(4) forces only A(i); compiler inserts its own counted vmcnt for
// the X register loads before first MFMA use (keeps A(i+1)/X(i+1) in flight).
__global__ __launch_bounds__(256, 3)
void k_gemm(const __hip_bfloat16* __restrict__ Abase, size_t astride,
            const __hip_bfloat16* __restrict__ XT,
            __hip_bfloat16* __restrict__ Ybase, size_t ystride) {
  __shared__ __align__(16) ushort At[2][128 * 32];   // 16 KB total
  const int t = threadIdx.x;
  // T1: XCD-chunked bijective swizzle (nwg % 8 == 0 for all launches).
  const int nwg = gridDim.x * gridDim.y * gridDim.z;
  const int orig = blockIdx.x + gridDim.x * (blockIdx.y + gridDim.y * blockIdx.z);
  const int chunk = nwg >> 3;
  const int swz = (orig & 7) * chunk + (orig >> 3);
  const int bx = swz % gridDim.x;
  const int rest = swz / gridDim.x;
  const int by = rest % gridDim.y;
  const int bz = rest / gridDim.y;
  const int j0 = bx * 128, r0 = by * 128;
  const ushort* Ag = (const ushort*)Abase + (size_t)bz * astride;
  ushort* Y = (ushort*)Ybase + (size_t)bz * ystride;
  const int lane = t & 63, w = t >> 6;
  const int rowa = w * 32 + (lane >> 2);
  // T2 (A side): pre-swizzled global source granule; LDS dest linear.
  const int kc = (((lane & 3) ^ ((lane >> 3) & 3)) * 8);
  const ushort* pA0 = Ag + (size_t)(r0 + rowa) * N_ + kc;
  const ushort* pA1 = pA0 + 16 * N_;
  const int l15 = t & 15, q = (t >> 4) & 3;
  const int qs = (q ^ ((l15 >> 1) & 3)) * 8;   // T2 read-side granule swizzle
  const int wr = (w >> 1) * 64, wc = (w & 1) * 64;
  // X per-lane direct pointers: row = j0 + wc + ni*16 + l15, k = q*8 (+32/iter)
  const ushort* pX0 = (const ushort*)XT + (size_t)(j0 + wc + l15) * N_ + q * 8;
  const ushort* pX1 = pX0 + (size_t)16 * N_;
  const ushort* pX2 = pX0 + (size_t)32 * N_;
  const ushort* pX3 = pX0 + (size_t)48 * N_;
  f4 acc[4][4];
  #pragma unroll
  for (int i = 0; i < 4; ++i)
    #pragma unroll
    for (int jj = 0; jj < 4; ++jj) acc[i][jj] = (f4)0.0f;
  // prologue: stage A(0) into buf0 (2 GLD16), load X(0) into xa regs
  GLD16(pA0, &At[0][(w * 32) * 32]);
  GLD16(pA1, &At[0][(w * 32 + 16) * 32]);
  pA0 += 32; pA1 += 32;
  s8 xa0 = *(const s8*)pX0, xa1 = *(const s8*)pX1;
  s8 xa2 = *(const s8*)pX2, xa3 = *(const s8*)pX3;
  pX0 += 32; pX1 += 32; pX2 += 32; pX3 += 32;
  s8 xb0 = {0,0,0,0,0,0,0,0}, xb1 = xb0, xb2 = xb0, xb3 = xb0;

  // Per sub-iter i (CUR=i&1): vmcnt(4) [outstanding: A(i)x2 then X(i)x4; force
  // A(i), X(i) waited by compiler-counted vmcnt before MFMA]; barrier publishes
  // A(i); stage A(i+1)->buf[i+1&1] (safe: its readers finished before barrier);
  // load X(i+1); ds_read A frags; 16 MFMA.
#define GSTEP(CUR, NXT, XC0, XC1, XC2, XC3, XN0, XN1, XN2, XN3, LAST)           \
  {                                                                             \
    asm volatile("s_waitcnt vmcnt(4)" ::: "memory");                            \
    __builtin_amdgcn_s_barrier();                                               \
    __builtin_amdgcn_sched_barrier(0);                                          \
    if (!(LAST)) {                                                              \
      GLD16(pA0, &At[NXT][(w * 32) * 32]);                                      \
      GLD16(pA1, &At[NXT][(w * 32 + 16) * 32]);                                 \
      pA0 += 32; pA1 += 32;                                                     \
      XN0 = *(const s8*)pX0; XN1 = *(const s8*)pX1;                             \
      XN2 = *(const s8*)pX2; XN3 = *(const s8*)pX3;                             \
      pX0 += 32; pX1 += 32; pX2 += 32; pX3 += 32;                               \
    }                                                                           \
    s8 af0 = *(const s8*)&At[CUR][(wr + 0 * 16 + l15) * 32 + qs];               \
    s8 af1 = *(const s8*)&At[CUR][(wr + 1 * 16 + l15) * 32 + qs];               \
    s8 af2 = *(const s8*)&At[CUR][(wr + 2 * 16 + l15) * 32 + qs];               \
    s8 af3 = *(const s8*)&At[CUR][(wr + 3 * 16 + l15) * 32 + qs];               \
    __builtin_amdgcn_s_setprio(1);                                              \
    acc[0][0] = __builtin_amdgcn_mfma_f32_16x16x32_bf16(af0, XC0, acc[0][0], 0, 0, 0); \
    acc[0][1] = __builtin_amdgcn_mfma_f32_16x16x32_bf16(af0, XC1, acc[0][1], 0, 0, 0); \
    acc[0][2] = __builtin_amdgcn_mfma_f32_16x16x32_bf16(af0, XC2, acc[0][2], 0, 0, 0); \
    acc[0][3] = __builtin_amdgcn_mfma_f32_16x16x32_bf16(af0, XC3, acc[0][3], 0, 0, 0); \
    acc[1][0] = __builtin_amdgcn_mfma_f32_16x16x32_bf16(af1, XC0, acc[1][0], 0, 0, 0); \
    acc[1][1] = __builtin_amdgcn_mfma_f32_16x16x32_bf16(af1, XC1, acc[1][1], 0, 0, 0); \
    acc[1][2] = __builtin_amdgcn_mfma_f32_16x16x32_bf16(af1, XC2, acc[1][2], 0, 0, 0); \
    acc[1][3] = __builtin_amdgcn_mfma_f32_16x16x32_bf16(af1, XC3, acc[1][3], 0, 0, 0); \
    acc[2][0] = __builtin_amdgcn_mfma_f32_16x16x32_bf16(af2, XC0, acc[2][0], 0, 0, 0); \
    acc[2][1] = __builtin_amdgcn_mfma_f32_16x16x32_bf16(af2, XC1, acc[2][1], 0, 0, 0); \
    acc[2][2] = __builtin_amdgcn_mfma_f32_16x16x32_bf16(af2, XC2, acc[2][2], 0, 0, 0); \
    acc[2][3] = __builtin_amdgcn_mfma_f32_16x16x32_bf16(af2, XC3, acc[2][3], 0, 0, 0); \
    acc[3][0] = __builtin_amdgcn_mfma_f32_16x16x32_bf16(af3, XC0, acc[3][0], 0, 0, 0); \
    acc[3][1] = __builtin_amdgcn_mfma_f32_16x16x32_bf16(af3, XC1, acc[3][1], 0, 0, 0); \
    acc[3][2] = __builtin_amdgcn_mfma_f32_16x16x32_bf16(af3, XC2, acc[3][2], 0, 0, 0); \
    acc[3][3] = __builtin_amdgcn_mfma_f32_16x16x32_bf16(af3, XC3, acc[3][3], 0, 0, 0); \
    __builtin_amdgcn_s_setprio(0);                                              \
  }

  for (int it = 0; it < 32; ++it) {
    GSTEP(0, 1, xa0, xa1, xa2, xa3, xb0, xb1, xb2, xb3, 0)
    GSTEP(1, 0, xb0, xb1, xb2, xb3, xa0, xa1, xa2, xa3, (it == 31))
  }
#undef GSTEP
  // C/D: col = lane&15, row = quad*4 + reg  [verified m89/m91]
  #pragma unroll
  for (int mi = 0; mi < 4; ++mi) {
    int rr = r0 + wr + mi * 16 + q * 4;
    #pragma unroll
    for (int ni = 0; ni < 4; ++ni) {
      int cc = j0 + wc + ni * 16 + l15;
      #pragma unroll
      for (int rg = 0; rg < 4; ++rg)
        Y[(size_t)(rr + rg) * CB + cc] = f2bf(acc[mi][ni][rg]);
    }
  }
}

// ---------------------------------------------------------------- Wm[n][o][KIP] bf16 = sum_d e[n,d] Wp[d,ki,o]
__global__ __launch_bounds__(256)
void k_wmat(const float* __restrict__ eg, const float* __restrict__ Wp, ushort* __restrict__ Wm) {
  constexpr int TRS = 36;
  __shared__ float Wl[16 * 8 * 64];     // [d][kr][o]  32 KB
  __shared__ ushort Tr[8 * 64 * TRS];   // [n][o][36]
  const int t = threadIdx.x;
  const int n0 = blockIdx.x * 8;
  const int y = blockIdx.y;
  const int o = t & 63, w = t >> 6;
  const int ng = w & 1, krh = (w >> 1) * 4;
  float er[4][16];
  #pragma unroll
  for (int j = 0; j < 4; ++j) {
    const float* ep = eg + (size_t)(n0 + ng * 4 + j) * D_;
    #pragma unroll
    for (int d = 0; d < D_; d += 4) {
      float4 v = *(const float4*)(ep + d);
      er[j][d] = v.x; er[j][d + 1] = v.y; er[j][d + 2] = v.z; er[j][d + 3] = v.w;
    }
  }
  const int ngroups = (y == 3) ? 2 : 1;
  for (int g = 0; g < ngroups; ++g) {
    const int kic0 = y * 4 + g * 4;
    for (int kk = 0; kk < 4; ++kk) {
      const int kic = kic0 + kk;
      __syncthreads();
      #pragma unroll
      for (int it = 0; it < 8; ++it) {
        int f = it * 256 + t;
        int d = f >> 7, rem = f & 127, kr = rem >> 4, o4 = rem & 15;
        int ki = kic * 8 + kr;
        float4 v;
        if (ki < KI) v = *(const float4*)&Wp[((size_t)d * KI + ki) * 64 + o4 * 4];
        else { v.x = 0.f; v.y = 0.f; v.z = 0.f; v.w = 0.f; }
        *(float4*)&Wl[f * 4] = v;
      }
      __syncthreads();
      float a[4][4];
      #pragma unroll
      for (int j = 0; j < 4; ++j)
        #pragma unroll
        for (int k = 0; k < 4; ++k) a[j][k] = 0.f;
      for (int d = 0; d < D_; ++d) {
        float w4[4];
        #pragma unroll
        for (int k = 0; k < 4; ++k) w4[k] = Wl[(d * 8 + krh + k) * 64 + o];
        #pragma unroll
        for (int j = 0; j < 4; ++j)
          #pragma unroll
          for (int k = 0; k < 4; ++k) a[j][k] = fmaf(er[j][d], w4[k], a[j][k]);
      }
      #pragma unroll
      for (int j = 0; j < 4; ++j) {
        ushort* tr = &Tr[((ng * 4 + j) * 64 + o) * TRS + kk * 8 + krh];
        *(uint*)&tr[0] = packbf(a[j][0], a[j][1]);
        *(uint*)&tr[2] = packbf(a[j][2], a[j][3]);
      }
    }
    __syncthreads();
    const int k0 = kic0 * 8;
    #pragma unroll
    for (int p = 0; p < 8; ++p) {
      int u = p * 256 + t;
      int nl = u >> 8, oo = (u >> 2) & 63, qq = u & 3;
      const ushort* tr = &Tr[(nl * 64 + oo) * TRS + qq * 8];
      uint2 lo = *(const uint2*)&tr[0];
      uint2 hi = *(const uint2*)&tr[4];
      uint4 vv; vv.x = lo.x; vv.y = lo.y; vv.z = hi.x; vv.w = hi.y;
      *(uint4*)&Wm[((size_t)(n0 + nl) * 64 + oo) * KIP + k0 + qq * 8] = vv;
    }
  }
}

// ---------------------------------------------------------------- per-node einsum via MFMA; B-frags direct from global Wm
template <int MODE>  // 0: sigmoid -> bf16 gate buf ; 1: tanh + GRU combine -> fp32 d_out
__global__ __launch_bounds__(256)
void k_einsum(const float* __restrict__ e, const ushort* __restrict__ Wm, const float* __restrict__ bp,
              const __hip_bfloat16* __restrict__ Y,
              const float* __restrict__ x, const float* __restrict__ state,
              const __hip_bfloat16* __restrict__ zbuf, const __hip_bfloat16* __restrict__ rbuf,
              void* __restrict__ outp) {
  constexpr int LDK = 168;
  constexpr int LDR = 72;
  __shared__ __align__(16) ushort xg[64 * LDK];
  __shared__ __align__(16) ushort res[64 * LDR];
  __shared__ float el[D_];
  __shared__ float bl[64];
  const int n = blockIdx.x, t = threadIdx.x;
  if (t < D_) el[t] = e[n * D_ + t];
  __syncthreads();
  if (t < 64) {
    float s = 0.f;
    #pragma unroll
    for (int d = 0; d < D_; ++d) s += el[d] * bp[d * 64 + t];
    bl[t] = s;
  }
  {
    const int b = t >> 2, j = t & 3;
    const size_t bn = (size_t)b * N_ + n;
    float sv[16];
    const float* sp = state + bn * 64 + j * 16;
    #pragma unroll
    for (int i = 0; i < 16; i += 4) {
      float4 v = *(const float4*)(sp + i);
      sv[i] = v.x; sv[i + 1] = v.y; sv[i + 2] = v.z; sv[i + 3] = v.w;
    }
    if (MODE) {
      const ushort* zp = (const ushort*)zbuf + bn * 64 + j * 16;
      uint4 z0 = *(const uint4*)&zp[0], z1 = *(const uint4*)&zp[8];
      uint zw[8] = {z0.x, z0.y, z0.z, z0.w, z1.x, z1.y, z1.z, z1.w};
      #pragma unroll
      for (int i = 0; i < 8; ++i) {
        sv[2 * i]     *= bf2f((ushort)(zw[i] & 0xffffu));
        sv[2 * i + 1] *= bf2f((ushort)(zw[i] >> 16));
      }
    }
    ushort* xr = &xg[b * LDK + 2 + j * 16];
    #pragma unroll
    for (int i = 0; i < 16; i += 2) {
      uint pk = packbf(sv[i], sv[i + 1]);
      *(uint*)&xr[i] = pk;
    }
    const ushort* yp = (const ushort*)Y + (size_t)n * CB + b * C_ + j * 16;
    uint* xy = (uint*)&xg[b * LDK + 66 + j * 16];
    #pragma unroll
    for (int i = 0; i < 8; ++i) xy[i] = *(const uint*)&yp[2 * i];
    if (j == 0) *(uint*)&xg[b * LDK + 130] = *(const uint*)&yp[64];
    if (t < 64) {
      const float* xp = x + ((size_t)t * N_ + n) * DIN;
      uint pk = packbf(xp[0], xp[1]);
      *(uint*)&xg[t * LDK] = pk;
    }
    ushort* pg = &xg[b * LDK + 132 + j * 7];
    #pragma unroll
    for (int i = 0; i < 7; ++i) pg[i] = 0;
  }
  __syncthreads();
  const int l15 = t & 15, q = (t >> 4) & 3, w = t >> 6;
  const int wm = (w >> 1) * 32, wn = (w & 1) * 32;
  const ushort* Wn = Wm + (size_t)n * (64 * KIP);
  f4 acc[2][2];
  acc[0][0] = acc[0][1] = acc[1][0] = acc[1][1] = (f4)0.0f;
  #pragma unroll
  for (int kk = 0; kk < KIP; kk += 32) {
    s8 af[2], bfr[2];
    #pragma unroll
    for (int mi = 0; mi < 2; ++mi) af[mi] = *(const s8*)&xg[(wm + mi * 16 + l15) * LDK + kk + q * 8];
    #pragma unroll
    for (int ni = 0; ni < 2; ++ni) bfr[ni] = *(const s8*)(Wn + (size_t)(wn + ni * 16 + l15) * KIP + kk + q * 8);
    #pragma unroll
    for (int mi = 0; mi < 2; ++mi)
      #pragma unroll
      for (int ni = 0; ni < 2; ++ni)
        acc[mi][ni] = __builtin_amdgcn_mfma_f32_16x16x32_bf16(af[mi], bfr[ni], acc[mi][ni], 0, 0, 0);
  }
  {
    float bl0 = bl[wn + l15], bl1 = bl[wn + 16 + l15];
    #pragma unroll
    for (int mi = 0; mi < 2; ++mi)
      #pragma unroll
      for (int ni = 0; ni < 2; ++ni) {
        float bb = ni ? bl1 : bl0;
        #pragma unroll
        for (int rg = 0; rg < 4; ++rg) {
          float v = acc[mi][ni][rg] + bb;
          float a;
          if (MODE == 0) a = 1.0f / (1.0f + __expf(-v));
          else           a = 1.0f - 2.0f / (__expf(2.0f * v) + 1.0f);
          res[(wm + mi * 16 + q * 4 + rg) * LDR + (wn + ni * 16 + l15)] = f2bf(a);
        }
      }
  }
  __syncthreads();
  {
    const int b = t >> 2, j = t & 3;
    const size_t gb = ((size_t)b * N_ + n) * 64 + j * 16;
    const ushort* rr = &res[b * LDR + j * 16];
    if (MODE == 0) {
      uint4 v0 = *(const uint4*)&rr[0];
      uint4 v1 = *(const uint4*)&rr[8];
      *(uint4*)((ushort*)outp + gb) = v0;
      *(uint4*)((ushort*)outp + gb + 8) = v1;
    } else {
      float* ob = (float*)outp;
      const float* stp = state + gb;
      const ushort* rp = (const ushort*)rbuf + gb;
      uint4 r0 = *(const uint4*)&rp[0], r1 = *(const uint4*)&rp[8];
      uint rw[8] = {r0.x, r0.y, r0.z, r0.w, r1.x, r1.y, r1.z, r1.w};
      #pragma unroll
      for (int i = 0; i < 16; i += 4) {
        float4 st = *(const float4*)(stp + i);
        float4 ov;
        float rv0 = bf2f((ushort)(rw[i / 2] & 0xffffu));
        float rv1 = bf2f((ushort)(rw[i / 2] >> 16));
        float rv2 = bf2f((ushort)(rw[i / 2 + 1] & 0xffffu));
        float rv3 = bf2f((ushort)(rw[i / 2 + 1] >> 16));
        ov.x = rv0 * st.x + (1.0f - rv0) * bf2f(rr[i]);
        ov.y = rv1 * st.y + (1.0f - rv1) * bf2f(rr[i + 1]);
        ov.z = rv2 * st.z + (1.0f - rv2) * bf2f(rr[i + 2]);
        ov.w = rv3 * st.w + (1.0f - rv3) * bf2f(rr[i + 3]);
        *(float4*)(ob + gb + i) = ov;
      }
    }
  }
}

// ----------------------------------------------------------------
extern "C" void kernel_launch(void* const* d_in, const int* in_sizes, int n_in,
                              void* d_out, int out_size, void* d_ws, size_t ws_size,
                              hipStream_t stream) {
  const float* x     = (const float*)d_in[0];
  const float* state = (const float*)d_in[1];
  const float* node  = (const float*)d_in[2];
  const float* timee = (const float*)d_in[3];
  const float* W_z = (const float*)d_in[4];
  const float* b_z = (const float*)d_in[5];
  const float* g_z = (const float*)d_in[6];
  const float* be_z = (const float*)d_in[7];
  const float* W_r = (const float*)d_in[8];
  const float* b_r = (const float*)d_in[9];
  const float* g_r = (const float*)d_in[10];
  const float* be_r = (const float*)d_in[11];
  const float* W_u = (const float*)d_in[12];
  const float* b_u = (const float*)d_in[13];
  const float* g_u = (const float*)d_in[14];
  const float* be_u = (const float*)d_in[15];

  constexpr size_t NN = (size_t)N_ * N_;
  constexpr size_t ND = (size_t)N_ * D_;
  char* ws = (char*)d_ws;
  float*           e  = (float*)(ws);                        //       0 :    393,216
  __hip_bfloat16*  A  = (__hip_bfloat16*)(ws + 393216);      //  25,165,824
  __hip_bfloat16*  XT = (__hip_bfloat16*)(ws + 25559040);    //  17,301,504
  __hip_bfloat16*  Y  = (__hip_bfloat16*)(ws + 42860544);    //  17,301,504
  __hip_bfloat16*  zb = (__hip_bfloat16*)(ws + 60162048);    //  16,777,216
  __hip_bfloat16*  rb = (__hip_bfloat16*)(ws + 76939264);    //  16,777,216
  ushort*          ebf = (ushort*)(ws + 93716480);           //  196,608 (dead before Wm written)
  ushort*          Wm = (ushort*)(ws + 93716480);            //  41,943,040 (ends 135,659,520)
  __hip_bfloat16*  Yr = (__hip_bfloat16*)(ws + 135659520);   //  17,301,504 (big-ws only)
  const size_t YRD = ((size_t)135659520 - 42860544) / 2;
  const bool big = ws_size >= (size_t)152961024;

  float* out = (float*)d_out;

  k_e<<<8, 256, 0, stream>>>(node, timee, g_z, be_z, g_r, be_r, g_u, be_u, e, ebf);
  k_attn<<<dim3(N_ / 16, 1, 3), 256, 0, stream>>>(ebf, A);
  k_buildX<0><<<dim3(32, 64), 256, 0, stream>>>(x, state, nullptr, XT);

  dim3 ggrid1(CB / 128, N_ / 128, 1);   // 528 blocks (%8==0)
  dim3 ggrid2(CB / 128, N_ / 128, 2);   // fused z+r: 1056 blocks (%8==0)
  dim3 wgrid(N_ / 8, 4);                // 1024 blocks

  if (big) {
    k_wmat<<<wgrid, 256, 0, stream>>>(e + 0 * ND, W_z, Wm);
    k_gemm<<<ggrid2, 256, 0, stream>>>(A, NN, XT, Y, YRD);                       // z->Y, r->Yr
    k_einsum<0><<<N_, 256, 0, stream>>>(e + 0 * ND, Wm, b_z, Y, x, state, nullptr, nullptr, (void*)zb);
    k_wmat<<<wgrid, 256, 0, stream>>>(e + 1 * ND, W_r, Wm);
    k_einsum<0><<<N_, 256, 0, stream>>>(e + 1 * ND, Wm, b_r, Yr, x, state, nullptr, nullptr, (void*)rb);
  } else {
    k_wmat<<<wgrid, 256, 0, stream>>>(e + 0 * ND, W_z, Wm);
    k_gemm<<<ggrid1, 256, 0, stream>>>(A, 0, XT, Y, 0);
    k_einsum<0><<<N_, 256, 0, stream>>>(e + 0 * ND, Wm, b_z, Y, x, state, nullptr, nullptr, (void*)zb);
    k_wmat<<<wgrid, 256, 0, stream>>>(e + 1 * ND, W_r, Wm);
    k_gemm<<<ggrid1, 256, 0, stream>>>(A + NN, 0, XT, Y, 0);
    k_einsum<0><<<N_, 256, 0, stream>>>(e + 1 * ND, Wm, b_r, Y, x, state, nullptr, nullptr, (void*)rb);
  }
  // gate u: cand = [x, z*state]
  k_buildX<1><<<dim3(32, 64), 256, 0, stream>>>(x, state, zb, XT);
  k_wmat<<<wgrid, 256, 0, stream>>>(e + 2 * ND, W_u, Wm);
  k_gemm<<<ggrid1, 256, 0, stream>>>(A + 2 * NN, 0, XT, Y, 0);
  k_einsum<1><<<N_, 256, 0, stream>>>(e + 2 * ND, Wm, b_u, Y, x, state, zb, rb, (void*)out);
}

// Round 6
// 537.579 us; speedup vs baseline: 1.1478x; 1.1478x over previous
//
#include <hip/hip_runtime.h>
#include <hip/hip_bf16.h>
#include <math.h>

// GRUCell with adaptive-graph GCN on MI355X (gfx950).
// B=64, N=2048, Din=2, H=64, D=16, C=66, O=64.
// R14: (1) REVERT k_gemm to R12 (single-barrier, 3-buf dist-2, vmcnt(4), T1/T2,
//      setprio) — R13's X-from-global regressed (16 lines/wave-load, L1 thrash,
//      FETCH +75MB, MfmaUtil 15%). 109.5us is the measured best for z+r.
//      (2) k_einsum: stage Wm[n] (20.5KB) into LDS with coalesced uint4 loads
//      issued BEFORE the xg build (T14 latency hiding), granule-XOR swizzle on
//      write+read (2 lanes/bank = free). Replaces the per-wave 320B-stride
//      global gather (16 cache lines per load-instr) in the MFMA K-loop.

typedef __attribute__((ext_vector_type(4))) float f4;
typedef __attribute__((ext_vector_type(8))) short s8;  // 8 bf16 in 4 VGPRs (MFMA A/B frag)

#define B_   64
#define N_   2048
#define DIN  2
#define H_   64
#define D_   16
#define C_   66    // DIN + H
#define KI   132   // 2*C
#define KIP  160   // KI padded for K-loop (multiple of 32)
#define CB   4224  // B_*C_

#define GLD16(gp, lp) __builtin_amdgcn_global_load_lds((const __attribute__((address_space(1))) void*)(gp), (__attribute__((address_space(3))) void*)(lp), 16, 0, 0)

static __device__ __forceinline__ ushort f2bf(float v) {
  __hip_bfloat16 h = __float2bfloat16(v);
  return *(ushort*)&h;
}
static __device__ __forceinline__ float bf2f(ushort u) {
  __hip_bfloat16 h = *(__hip_bfloat16*)&u;
  return __bfloat162float(h);
}
static __device__ __forceinline__ uint packbf(float a, float b) {
  return ((uint)f2bf(b) << 16) | f2bf(a);
}

// ---------------------------------------------------------------- e = LN(node+time)*gamma+beta (fp32 + bf16 copies)
__global__ void k_e(const float* __restrict__ node, const float* __restrict__ timee,
                    const float* __restrict__ g0, const float* __restrict__ b0,
                    const float* __restrict__ g1, const float* __restrict__ b1,
                    const float* __restrict__ g2, const float* __restrict__ b2,
                    float* __restrict__ e, ushort* __restrict__ ebf) {
  int n = blockIdx.x * blockDim.x + threadIdx.x;
  if (n >= N_) return;
  float v[D_]; float m = 0.f;
  #pragma unroll
  for (int d = 0; d < D_; ++d) { v[d] = node[n * D_ + d] + timee[d]; m += v[d]; }
  m *= (1.0f / D_);
  float var = 0.f;
  #pragma unroll
  for (int d = 0; d < D_; ++d) { float t = v[d] - m; var += t * t; }
  var *= (1.0f / D_);
  float r = rsqrtf(var + 1e-12f);
  float y[D_];
  #pragma unroll
  for (int d = 0; d < D_; ++d) y[d] = (v[d] - m) * r;
  const float* gs[3] = {g0, g1, g2};
  const float* bs[3] = {b0, b1, b2};
  #pragma unroll
  for (int g = 0; g < 3; ++g) {
    #pragma unroll
    for (int d = 0; d < D_; d += 2) {
      float o0 = y[d] * gs[g][d] + bs[g][d];
      float o1 = y[d + 1] * gs[g][d + 1] + bs[g][d + 1];
      e[g * N_ * D_ + n * D_ + d] = o0;
      e[g * N_ * D_ + n * D_ + d + 1] = o1;
      *(uint*)&ebf[g * N_ * D_ + n * D_ + d] = packbf(o0, o1);
    }
  }
}

// ---------------------------------------------------------------- fused A_g = softmax(e_g e_g^T, axis=1), bf16
__global__ __launch_bounds__(256)
void k_attn(const ushort* __restrict__ ebf, __hip_bfloat16* __restrict__ A) {
  __shared__ __align__(16) ushort eb[N_ * D_];   // 64 KB
  __shared__ float red[4][16];
  const int t = threadIdx.x;
  const ushort* eg = ebf + (size_t)blockIdx.z * (N_ * D_);
  {
    const uint4* src = (const uint4*)eg;
    uint4* dst = (uint4*)eb;
    #pragma unroll
    for (int i = 0; i < 16; ++i) dst[i * 256 + t] = src[i * 256 + t];
  }
  __syncthreads();
  const int lane = t & 63, w = t >> 6;
  const int l15 = lane & 15, q = lane >> 4;
  const int r0 = blockIdx.x * 16;
  s8 rf = {0, 0, 0, 0, 0, 0, 0, 0};
  if (q < 2) rf = *(const s8*)&eb[(r0 + l15) * D_ + q * 8];
  const int c0 = w * 512;
  f4 acc[32];
  #pragma unroll
  for (int tl = 0; tl < 32; ++tl) {
    s8 cf = {0, 0, 0, 0, 0, 0, 0, 0};
    if (q < 2) cf = *(const s8*)&eb[(c0 + tl * 16 + l15) * D_ + q * 8];
    acc[tl] = __builtin_amdgcn_mfma_f32_16x16x32_bf16(cf, rf, (f4)0.0f, 0, 0, 0);
  }
  float m = acc[0][0];
  #pragma unroll
  for (int tl = 0; tl < 32; ++tl) {
    #pragma unroll
    for (int rg = 0; rg < 4; ++rg) m = fmaxf(m, acc[tl][rg]);
  }
  m = fmaxf(m, __shfl_xor(m, 16, 64));
  m = fmaxf(m, __shfl_xor(m, 32, 64));
  if (lane < 16) red[w][l15] = m;
  __syncthreads();
  const float gm = fmaxf(fmaxf(red[0][l15], red[1][l15]), fmaxf(red[2][l15], red[3][l15]));
  __syncthreads();
  float ps = 0.f;
  #pragma unroll
  for (int tl = 0; tl < 32; ++tl) {
    #pragma unroll
    for (int rg = 0; rg < 4; ++rg) {
      float v = __expf(acc[tl][rg] - gm);
      acc[tl][rg] = v;
      ps += v;
    }
  }
  ps += __shfl_xor(ps, 16, 64);
  ps += __shfl_xor(ps, 32, 64);
  if (lane < 16) red[w][l15] = ps;
  __syncthreads();
  const float inv = 1.0f / (red[0][l15] + red[1][l15] + red[2][l15] + red[3][l15]);
  ushort* Ar = (ushort*)A + (size_t)blockIdx.z * ((size_t)N_ * N_) +
               (size_t)(r0 + l15) * N_ + c0 + q * 4;
  #pragma unroll
  for (int tl = 0; tl < 32; ++tl) {
    uint2 pk;
    pk.x = packbf(acc[tl][0] * inv, acc[tl][1] * inv);
    pk.y = packbf(acc[tl][2] * inv, acc[tl][3] * inv);
    *(uint2*)&Ar[tl * 16] = pk;
  }
}

// ---------------------------------------------------------------- X^T[j=b*C+c][m] bf16 via LDS transpose
template <int MODE>  // 0: xs=[x,state]   1: cand=[x, z*state]
__global__ __launch_bounds__(256)
void k_buildX(const float* __restrict__ x, const float* __restrict__ state,
              const __hip_bfloat16* __restrict__ zbuf, __hip_bfloat16* __restrict__ XT) {
  constexpr int LDM = 72;
  __shared__ __align__(16) ushort T[C_ * LDM];
  const int t = threadIdx.x;
  const int m0 = blockIdx.x * 64, b = blockIdx.y;
  const int m = t >> 2, hq = t & 3;
  {
    const float* sp = state + ((size_t)b * N_ + m0 + m) * H_ + hq * 16;
    float sv[16];
    #pragma unroll
    for (int i = 0; i < 16; i += 4) {
      float4 v = *(const float4*)(sp + i);
      sv[i] = v.x; sv[i + 1] = v.y; sv[i + 2] = v.z; sv[i + 3] = v.w;
    }
    if (MODE) {
      const ushort* zp = (const ushort*)zbuf + ((size_t)b * N_ + m0 + m) * H_ + hq * 16;
      uint4 z0 = *(const uint4*)&zp[0], z1 = *(const uint4*)&zp[8];
      uint zw[8] = {z0.x, z0.y, z0.z, z0.w, z1.x, z1.y, z1.z, z1.w};
      #pragma unroll
      for (int i = 0; i < 8; ++i) {
        sv[2 * i]     *= bf2f((ushort)(zw[i] & 0xffffu));
        sv[2 * i + 1] *= bf2f((ushort)(zw[i] >> 16));
      }
    }
    #pragma unroll
    for (int i = 0; i < 16; ++i) T[(DIN + hq * 16 + i) * LDM + m] = f2bf(sv[i]);
    if (t < 64) {
      const float2 xv = *(const float2*)&x[((size_t)b * N_ + m0 + t) * DIN];
      T[0 * LDM + t] = f2bf(xv.x);
      T[1 * LDM + t] = f2bf(xv.y);
    }
  }
  __syncthreads();
  {
    int r = t >> 2, ch = t & 3;
    ushort* dst = (ushort*)XT + (size_t)(b * C_ + r) * N_ + m0 + ch * 16;
    *(uint4*)&dst[0] = *(uint4*)&T[r * LDM + ch * 16];
    *(uint4*)&dst[8] = *(uint4*)&T[r * LDM + ch * 16 + 8];
    if (t < 8) {
      r = 64 + (t >> 2);
      ushort* dst2 = (ushort*)XT + (size_t)(b * C_ + r) * N_ + m0 + ch * 16;
      *(uint4*)&dst2[0] = *(uint4*)&T[r * LDM + ch * 16];
      *(uint4*)&dst2[8] = *(uint4*)&T[r * LDM + ch * 16 + 8];
    }
  }
}

// ---------------------------------------------------------------- Y[r,j] = sum_m A[r,m] XT[j,m]
// R12-exact (measured best 109.5us z+r): SINGLE barrier per K-tile; 3-buffer
// distance-2 prefetch, counted vmcnt(4); T1 XCD swizzle; T2 both-sides LDS
// swizzle; T5 setprio.
__global__ __launch_bounds__(256)
void k_gemm(const __hip_bfloat16* __restrict__ Abase, size_t astride,
            const __hip_bfloat16* __restrict__ XT,
            __hip_bfloat16* __restrict__ Ybase, size_t ystride) {
  __shared__ __align__(16) ushort At[3][128 * 32];
  __shared__ __align__(16) ushort Xt[3][128 * 32];
  const int t = threadIdx.x;
  const int nwg = gridDim.x * gridDim.y * gridDim.z;   // 1056 or 528, both %8==0
  const int orig = blockIdx.x + gridDim.x * (blockIdx.y + gridDim.y * blockIdx.z);
  const int chunk = nwg >> 3;
  const int swz = (orig & 7) * chunk + (orig >> 3);
  const int bx = swz % gridDim.x;
  const int rest = swz / gridDim.x;
  const int by = rest % gridDim.y;
  const int bz = rest / gridDim.y;
  const int j0 = bx * 128, r0 = by * 128;
  const ushort* Ag = (const ushort*)Abase + (size_t)bz * astride;
  ushort* Y = (ushort*)Ybase + (size_t)bz * ystride;
  const int lane = t & 63, w = t >> 6;
  const int rowa = w * 32 + (lane >> 2);
  const int kc = (((lane & 3) ^ ((lane >> 3) & 3)) * 8);
  const ushort* pA0 = Ag + (size_t)(r0 + rowa) * N_ + kc;
  const ushort* pA1 = pA0 + 16 * N_;
  const ushort* pX0 = (const ushort*)XT + (size_t)(j0 + rowa) * N_ + kc;
  const ushort* pX1 = pX0 + 16 * N_;
  const int l15 = t & 15, q = (t >> 4) & 3;
  const int qs = (q ^ ((l15 >> 1) & 3)) * 8;
  const int wr = (w >> 1) * 64, wc = (w & 1) * 64;
  f4 acc[4][4];
  #pragma unroll
  for (int i = 0; i < 4; ++i)
    #pragma unroll
    for (int jj = 0; jj < 4; ++jj) acc[i][jj] = (f4)0.0f;
  #pragma unroll
  for (int p = 0; p < 2; ++p) {
    GLD16(pA0, &At[p][(w * 32) * 32]);
    GLD16(pA1, &At[p][(w * 32 + 16) * 32]);
    GLD16(pX0, &Xt[p][(w * 32) * 32]);
    GLD16(pX1, &Xt[p][(w * 32 + 16) * 32]);
    pA0 += 32; pA1 += 32; pX0 += 32; pX1 += 32;
  }
  int cur = 0, nx = 2;
  for (int k0 = 0; k0 < N_; k0 += 32) {
    if (k0 + 32 < N_) asm volatile("s_waitcnt vmcnt(4)" ::: "memory");
    else              asm volatile("s_waitcnt vmcnt(0)" ::: "memory");
    __builtin_amdgcn_s_barrier();           // tile-i data visible; tile-(i-1) reads done
    __builtin_amdgcn_sched_barrier(0);
    if (k0 + 64 < N_) {
      GLD16(pA0, &At[nx][(w * 32) * 32]);
      GLD16(pA1, &At[nx][(w * 32 + 16) * 32]);
      GLD16(pX0, &Xt[nx][(w * 32) * 32]);
      GLD16(pX1, &Xt[nx][(w * 32 + 16) * 32]);
      pA0 += 32; pA1 += 32; pX0 += 32; pX1 += 32;
    }
    s8 af[4], bfr[4];
    #pragma unroll
    for (int mi = 0; mi < 4; ++mi)
      af[mi] = *(const s8*)&At[cur][(wr + mi * 16 + l15) * 32 + qs];
    #pragma unroll
    for (int ni = 0; ni < 4; ++ni)
      bfr[ni] = *(const s8*)&Xt[cur][(wc + ni * 16 + l15) * 32 + qs];
    __builtin_amdgcn_s_setprio(1);
    #pragma unroll
    for (int mi = 0; mi < 4; ++mi)
      #pragma unroll
      for (int ni = 0; ni < 4; ++ni)
        acc[mi][ni] = __builtin_amdgcn_mfma_f32_16x16x32_bf16(af[mi], bfr[ni], acc[mi][ni], 0, 0, 0);
    __builtin_amdgcn_s_setprio(0);
    cur = cur == 2 ? 0 : cur + 1;
    nx = nx == 2 ? 0 : nx + 1;
  }
  // C/D: col = lane&15, row = quad*4 + reg  [verified m89/m91]
  #pragma unroll
  for (int mi = 0; mi < 4; ++mi) {
    int rr = r0 + wr + mi * 16 + q * 4;
    #pragma unroll
    for (int ni = 0; ni < 4; ++ni) {
      int cc = j0 + wc + ni * 16 + l15;
      #pragma unroll
      for (int rg = 0; rg < 4; ++rg)
        Y[(size_t)(rr + rg) * CB + cc] = f2bf(acc[mi][ni][rg]);
    }
  }
}

// ---------------------------------------------------------------- Wm[n][o][KIP] bf16 = sum_d e[n,d] Wp[d,ki,o]
__global__ __launch_bounds__(256)
void k_wmat(const float* __restrict__ eg, const float* __restrict__ Wp, ushort* __restrict__ Wm) {
  constexpr int TRS = 36;
  __shared__ float Wl[16 * 8 * 64];     // [d][kr][o]  32 KB
  __shared__ ushort Tr[8 * 64 * TRS];   // [n][o][36]
  const int t = threadIdx.x;
  const int n0 = blockIdx.x * 8;
  const int y = blockIdx.y;
  const int o = t & 63, w = t >> 6;
  const int ng = w & 1, krh = (w >> 1) * 4;
  float er[4][16];
  #pragma unroll
  for (int j = 0; j < 4; ++j) {
    const float* ep = eg + (size_t)(n0 + ng * 4 + j) * D_;
    #pragma unroll
    for (int d = 0; d < D_; d += 4) {
      float4 v = *(const float4*)(ep + d);
      er[j][d] = v.x; er[j][d + 1] = v.y; er[j][d + 2] = v.z; er[j][d + 3] = v.w;
    }
  }
  const int ngroups = (y == 3) ? 2 : 1;
  for (int g = 0; g < ngroups; ++g) {
    const int kic0 = y * 4 + g * 4;
    for (int kk = 0; kk < 4; ++kk) {
      const int kic = kic0 + kk;
      __syncthreads();
      #pragma unroll
      for (int it = 0; it < 8; ++it) {
        int f = it * 256 + t;
        int d = f >> 7, rem = f & 127, kr = rem >> 4, o4 = rem & 15;
        int ki = kic * 8 + kr;
        float4 v;
        if (ki < KI) v = *(const float4*)&Wp[((size_t)d * KI + ki) * 64 + o4 * 4];
        else { v.x = 0.f; v.y = 0.f; v.z = 0.f; v.w = 0.f; }
        *(float4*)&Wl[f * 4] = v;
      }
      __syncthreads();
      float a[4][4];
      #pragma unroll
      for (int j = 0; j < 4; ++j)
        #pragma unroll
        for (int k = 0; k < 4; ++k) a[j][k] = 0.f;
      for (int d = 0; d < D_; ++d) {
        float w4[4];
        #pragma unroll
        for (int k = 0; k < 4; ++k) w4[k] = Wl[(d * 8 + krh + k) * 64 + o];
        #pragma unroll
        for (int j = 0; j < 4; ++j)
          #pragma unroll
          for (int k = 0; k < 4; ++k) a[j][k] = fmaf(er[j][d], w4[k], a[j][k]);
      }
      #pragma unroll
      for (int j = 0; j < 4; ++j) {
        ushort* tr = &Tr[((ng * 4 + j) * 64 + o) * TRS + kk * 8 + krh];
        *(uint*)&tr[0] = packbf(a[j][0], a[j][1]);
        *(uint*)&tr[2] = packbf(a[j][2], a[j][3]);
      }
    }
    __syncthreads();
    const int k0 = kic0 * 8;
    #pragma unroll
    for (int p = 0; p < 8; ++p) {
      int u = p * 256 + t;
      int nl = u >> 8, oo = (u >> 2) & 63, qq = u & 3;
      const ushort* tr = &Tr[(nl * 64 + oo) * TRS + qq * 8];
      uint2 lo = *(const uint2*)&tr[0];
      uint2 hi = *(const uint2*)&tr[4];
      uint4 vv; vv.x = lo.x; vv.y = lo.y; vv.z = hi.x; vv.w = hi.y;
      *(uint4*)&Wm[((size_t)(n0 + nl) * 64 + oo) * KIP + k0 + qq * 8] = vv;
    }
  }
}

// ---------------------------------------------------------------- per-node einsum via MFMA
// R14: Wm[n] (20.5KB) staged coalesced into LDS (loads issued before xg build —
// T14), granule-XOR swizzle write+read; MFMA B-frags from LDS (was a 320B-stride
// global gather, 16 cache lines per wave-load).
template <int MODE>  // 0: sigmoid -> bf16 gate buf ; 1: tanh + GRU combine -> fp32 d_out
__global__ __launch_bounds__(256)
void k_einsum(const float* __restrict__ e, const ushort* __restrict__ Wm, const float* __restrict__ bp,
              const __hip_bfloat16* __restrict__ Y,
              const float* __restrict__ x, const float* __restrict__ state,
              const __hip_bfloat16* __restrict__ zbuf, const __hip_bfloat16* __restrict__ rbuf,
              void* __restrict__ outp) {
  constexpr int LDK = 168;
  constexpr int LDR = 72;
  __shared__ __align__(16) ushort xg[64 * LDK];
  __shared__ __align__(16) ushort wl[64 * KIP];   // 20.5 KB, [o][KIP] granule-swizzled
  __shared__ __align__(16) ushort res[64 * LDR];
  __shared__ float el[D_];
  __shared__ float bl[64];
  const int n = blockIdx.x, t = threadIdx.x;
  // T14: issue the Wm stage loads FIRST; latency hides under the xg build.
  const ushort* Wn = Wm + (size_t)n * (64 * KIP);
  uint4 wreg[5];
  #pragma unroll
  for (int i = 0; i < 5; ++i) wreg[i] = *(const uint4*)(Wn + (i * 256 + t) * 8);
  if (t < D_) el[t] = e[n * D_ + t];
  __syncthreads();
  if (t < 64) {
    float s = 0.f;
    #pragma unroll
    for (int d = 0; d < D_; ++d) s += el[d] * bp[d * 64 + t];
    bl[t] = s;
  }
  {
    const int b = t >> 2, j = t & 3;
    const size_t bn = (size_t)b * N_ + n;
    float sv[16];
    const float* sp = state + bn * 64 + j * 16;
    #pragma unroll
    for (int i = 0; i < 16; i += 4) {
      float4 v = *(const float4*)(sp + i);
      sv[i] = v.x; sv[i + 1] = v.y; sv[i + 2] = v.z; sv[i + 3] = v.w;
    }
    if (MODE) {
      const ushort* zp = (const ushort*)zbuf + bn * 64 + j * 16;
      uint4 z0 = *(const uint4*)&zp[0], z1 = *(const uint4*)&zp[8];
      uint zw[8] = {z0.x, z0.y, z0.z, z0.w, z1.x, z1.y, z1.z, z1.w};
      #pragma unroll
      for (int i = 0; i < 8; ++i) {
        sv[2 * i]     *= bf2f((ushort)(zw[i] & 0xffffu));
        sv[2 * i + 1] *= bf2f((ushort)(zw[i] >> 16));
      }
    }
    ushort* xr = &xg[b * LDK + 2 + j * 16];
    #pragma unroll
    for (int i = 0; i < 16; i += 2) {
      uint pk = packbf(sv[i], sv[i + 1]);
      *(uint*)&xr[i] = pk;
    }
    const ushort* yp = (const ushort*)Y + (size_t)n * CB + b * C_ + j * 16;
    uint* xy = (uint*)&xg[b * LDK + 66 + j * 16];
    #pragma unroll
    for (int i = 0; i < 8; ++i) xy[i] = *(const uint*)&yp[2 * i];
    if (j == 0) *(uint*)&xg[b * LDK + 130] = *(const uint*)&yp[64];
    if (t < 64) {
      const float* xp = x + ((size_t)t * N_ + n) * DIN;
      uint pk = packbf(xp[0], xp[1]);
      *(uint*)&xg[t * LDK] = pk;
    }
    ushort* pg = &xg[b * LDK + 132 + j * 7];
    #pragma unroll
    for (int i = 0; i < 7; ++i) pg[i] = 0;
  }
  // write staged Wm to LDS, granule-swizzled: logical (o, c) stored with
  // granule g -> g ^ ((o>>1)&3) within each 32-short window (read uses same).
  #pragma unroll
  for (int i = 0; i < 5; ++i) {
    int j = (i * 256 + t) * 8;          // short index, granule-aligned
    int o = j / KIP;
    int c = j - o * KIP;
    int g = (c >> 3) & 3;
    int cs = (c & ~24) | (((g ^ ((o >> 1) & 3)) & 3) << 3);
    *(uint4*)&wl[o * KIP + cs] = wreg[i];
  }
  __syncthreads();
  const int l15 = t & 15, q = (t >> 4) & 3, w = t >> 6;
  const int qs = (q ^ ((l15 >> 1) & 3)) * 8;   // B-frag read granule swizzle
  const int wm = (w >> 1) * 32, wn = (w & 1) * 32;
  f4 acc[2][2];
  acc[0][0] = acc[0][1] = acc[1][0] = acc[1][1] = (f4)0.0f;
  #pragma unroll
  for (int kk = 0; kk < KIP; kk += 32) {
    s8 af[2], bfr[2];
    #pragma unroll
    for (int mi = 0; mi < 2; ++mi) af[mi] = *(const s8*)&xg[(wm + mi * 16 + l15) * LDK + kk + q * 8];
    #pragma unroll
    for (int ni = 0; ni < 2; ++ni) bfr[ni] = *(const s8*)&wl[(wn + ni * 16 + l15) * KIP + kk + qs];
    #pragma unroll
    for (int mi = 0; mi < 2; ++mi)
      #pragma unroll
      for (int ni = 0; ni < 2; ++ni)
        acc[mi][ni] = __builtin_amdgcn_mfma_f32_16x16x32_bf16(af[mi], bfr[ni], acc[mi][ni], 0, 0, 0);
  }
  {
    float bl0 = bl[wn + l15], bl1 = bl[wn + 16 + l15];
    #pragma unroll
    for (int mi = 0; mi < 2; ++mi)
      #pragma unroll
      for (int ni = 0; ni < 2; ++ni) {
        float bb = ni ? bl1 : bl0;
        #pragma unroll
        for (int rg = 0; rg < 4; ++rg) {
          float v = acc[mi][ni][rg] + bb;
          float a;
          if (MODE == 0) a = 1.0f / (1.0f + __expf(-v));
          else           a = 1.0f - 2.0f / (__expf(2.0f * v) + 1.0f);
          res[(wm + mi * 16 + q * 4 + rg) * LDR + (wn + ni * 16 + l15)] = f2bf(a);
        }
      }
  }
  __syncthreads();
  {
    const int b = t >> 2, j = t & 3;
    const size_t gb = ((size_t)b * N_ + n) * 64 + j * 16;
    const ushort* rr = &res[b * LDR + j * 16];
    if (MODE == 0) {
      uint4 v0 = *(const uint4*)&rr[0];
      uint4 v1 = *(const uint4*)&rr[8];
      *(uint4*)((ushort*)outp + gb) = v0;
      *(uint4*)((ushort*)outp + gb + 8) = v1;
    } else {
      float* ob = (float*)outp;
      const float* stp = state + gb;
      const ushort* rp = (const ushort*)rbuf + gb;
      uint4 r0 = *(const uint4*)&rp[0], r1 = *(const uint4*)&rp[8];
      uint rw[8] = {r0.x, r0.y, r0.z, r0.w, r1.x, r1.y, r1.z, r1.w};
      #pragma unroll
      for (int i = 0; i < 16; i += 4) {
        float4 st = *(const float4*)(stp + i);
        float4 ov;
        float rv0 = bf2f((ushort)(rw[i / 2] & 0xffffu));
        float rv1 = bf2f((ushort)(rw[i / 2] >> 16));
        float rv2 = bf2f((ushort)(rw[i / 2 + 1] & 0xffffu));
        float rv3 = bf2f((ushort)(rw[i / 2 + 1] >> 16));
        ov.x = rv0 * st.x + (1.0f - rv0) * bf2f(rr[i]);
        ov.y = rv1 * st.y + (1.0f - rv1) * bf2f(rr[i + 1]);
        ov.z = rv2 * st.z + (1.0f - rv2) * bf2f(rr[i + 2]);
        ov.w = rv3 * st.w + (1.0f - rv3) * bf2f(rr[i + 3]);
        *(float4*)(ob + gb + i) = ov;
      }
    }
  }
}

// ----------------------------------------------------------------
extern "C" void kernel_launch(void* const* d_in, const int* in_sizes, int n_in,
                              void* d_out, int out_size, void* d_ws, size_t ws_size,
                              hipStream_t stream) {
  const float* x     = (const float*)d_in[0];
  const float* state = (const float*)d_in[1];
  const float* node  = (const float*)d_in[2];
  const float* timee = (const float*)d_in[3];
  const float* W_z = (const float*)d_in[4];
  const float* b_z = (const float*)d_in[5];
  const float* g_z = (const float*)d_in[6];
  const float* be_z = (const float*)d_in[7];
  const float* W_r = (const float*)d_in[8];
  const float* b_r = (const float*)d_in[9];
  const float* g_r = (const float*)d_in[10];
  const float* be_r = (const float*)d_in[11];
  const float* W_u = (const float*)d_in[12];
  const float* b_u = (const float*)d_in[13];
  const float* g_u = (const float*)d_in[14];
  const float* be_u = (const float*)d_in[15];

  constexpr size_t NN = (size_t)N_ * N_;
  constexpr size_t ND = (size_t)N_ * D_;
  char* ws = (char*)d_ws;
  float*           e  = (float*)(ws);                        //       0 :    393,216
  __hip_bfloat16*  A  = (__hip_bfloat16*)(ws + 393216);      //  25,165,824
  __hip_bfloat16*  XT = (__hip_bfloat16*)(ws + 25559040);    //  17,301,504
  __hip_bfloat16*  Y  = (__hip_bfloat16*)(ws + 42860544);    //  17,301,504
  __hip_bfloat16*  zb = (__hip_bfloat16*)(ws + 60162048);    //  16,777,216
  __hip_bfloat16*  rb = (__hip_bfloat16*)(ws + 76939264);    //  16,777,216
  ushort*          ebf = (ushort*)(ws + 93716480);           //  196,608 (dead before Wm written)
  ushort*          Wm = (ushort*)(ws + 93716480);            //  41,943,040 (ends 135,659,520)
  __hip_bfloat16*  Yr = (__hip_bfloat16*)(ws + 135659520);   //  17,301,504 (big-ws only)
  const size_t YRD = ((size_t)135659520 - 42860544) / 2;
  const bool big = ws_size >= (size_t)152961024;

  float* out = (float*)d_out;

  k_e<<<8, 256, 0, stream>>>(node, timee, g_z, be_z, g_r, be_r, g_u, be_u, e, ebf);
  k_attn<<<dim3(N_ / 16, 1, 3), 256, 0, stream>>>(ebf, A);
  k_buildX<0><<<dim3(32, 64), 256, 0, stream>>>(x, state, nullptr, XT);

  dim3 ggrid1(CB / 128, N_ / 128, 1);   // 528 blocks (%8==0)
  dim3 ggrid2(CB / 128, N_ / 128, 2);   // fused z+r: 1056 blocks (%8==0)
  dim3 wgrid(N_ / 8, 4);                // 1024 blocks

  if (big) {
    k_wmat<<<wgrid, 256, 0, stream>>>(e + 0 * ND, W_z, Wm);
    k_gemm<<<ggrid2, 256, 0, stream>>>(A, NN, XT, Y, YRD);                       // z->Y, r->Yr
    k_einsum<0><<<N_, 256, 0, stream>>>(e + 0 * ND, Wm, b_z, Y, x, state, nullptr, nullptr, (void*)zb);
    k_wmat<<<wgrid, 256, 0, stream>>>(e + 1 * ND, W_r, Wm);
    k_einsum<0><<<N_, 256, 0, stream>>>(e + 1 * ND, Wm, b_r, Yr, x, state, nullptr, nullptr, (void*)rb);
  } else {
    k_wmat<<<wgrid, 256, 0, stream>>>(e + 0 * ND, W_z, Wm);
    k_gemm<<<ggrid1, 256, 0, stream>>>(A, 0, XT, Y, 0);
    k_einsum<0><<<N_, 256, 0, stream>>>(e + 0 * ND, Wm, b_z, Y, x, state, nullptr, nullptr, (void*)zb);
    k_wmat<<<wgrid, 256, 0, stream>>>(e + 1 * ND, W_r, Wm);
    k_gemm<<<ggrid1, 256, 0, stream>>>(A + NN, 0, XT, Y, 0);
    k_einsum<0><<<N_, 256, 0, stream>>>(e + 1 * ND, Wm, b_r, Y, x, state, nullptr, nullptr, (void*)rb);
  }
  // gate u: cand = [x, z*state]
  k_buildX<1><<<dim3(32, 64), 256, 0, stream>>>(x, state, zb, XT);
  k_wmat<<<wgrid, 256, 0, stream>>>(e + 2 * ND, W_u, Wm);
  k_gemm<<<ggrid1, 256, 0, stream>>>(A + 2 * NN, 0, XT, Y, 0);
  k_einsum<1><<<N_, 256, 0, stream>>>(e + 2 * ND, Wm, b_u, Y, x, state, zb, rb, (void*)out);
}

// Round 7
// 498.686 us; speedup vs baseline: 1.2374x; 1.0780x over previous
//
#include <hip/hip_runtime.h>
#include <hip/hip_bf16.h>
#include <math.h>

// GRUCell with adaptive-graph GCN on MI355X (gfx950).
// B=64, N=2048, Din=2, H=64, D=16, C=66, O=64.
// R15: (1) REVERT k_einsum to R12 global-gather (R14's LDS staging cost 35us:
//      Wm[n] has zero reuse -> staging saved no traffic, only occupancy 5->3).
//      (2) k_wmat load-balance: grid y=0..4 uniform (4 kic each) instead of
//      y==3 doing double work (256/1024 blocks were 2x stragglers, x3 dispatches).
//      k_gemm stays R12-best (109-114us plateau across 6 variants — m233's
//      2-phase structural ceiling; not touching it again).

typedef __attribute__((ext_vector_type(4))) float f4;
typedef __attribute__((ext_vector_type(8))) short s8;  // 8 bf16 in 4 VGPRs (MFMA A/B frag)

#define B_   64
#define N_   2048
#define DIN  2
#define H_   64
#define D_   16
#define C_   66    // DIN + H
#define KI   132   // 2*C
#define KIP  160   // KI padded for K-loop (multiple of 32)
#define CB   4224  // B_*C_

#define GLD16(gp, lp) __builtin_amdgcn_global_load_lds((const __attribute__((address_space(1))) void*)(gp), (__attribute__((address_space(3))) void*)(lp), 16, 0, 0)

static __device__ __forceinline__ ushort f2bf(float v) {
  __hip_bfloat16 h = __float2bfloat16(v);
  return *(ushort*)&h;
}
static __device__ __forceinline__ float bf2f(ushort u) {
  __hip_bfloat16 h = *(__hip_bfloat16*)&u;
  return __bfloat162float(h);
}
static __device__ __forceinline__ uint packbf(float a, float b) {
  return ((uint)f2bf(b) << 16) | f2bf(a);
}

// ---------------------------------------------------------------- e = LN(node+time)*gamma+beta (fp32 + bf16 copies)
__global__ void k_e(const float* __restrict__ node, const float* __restrict__ timee,
                    const float* __restrict__ g0, const float* __restrict__ b0,
                    const float* __restrict__ g1, const float* __restrict__ b1,
                    const float* __restrict__ g2, const float* __restrict__ b2,
                    float* __restrict__ e, ushort* __restrict__ ebf) {
  int n = blockIdx.x * blockDim.x + threadIdx.x;
  if (n >= N_) return;
  float v[D_]; float m = 0.f;
  #pragma unroll
  for (int d = 0; d < D_; ++d) { v[d] = node[n * D_ + d] + timee[d]; m += v[d]; }
  m *= (1.0f / D_);
  float var = 0.f;
  #pragma unroll
  for (int d = 0; d < D_; ++d) { float t = v[d] - m; var += t * t; }
  var *= (1.0f / D_);
  float r = rsqrtf(var + 1e-12f);
  float y[D_];
  #pragma unroll
  for (int d = 0; d < D_; ++d) y[d] = (v[d] - m) * r;
  const float* gs[3] = {g0, g1, g2};
  const float* bs[3] = {b0, b1, b2};
  #pragma unroll
  for (int g = 0; g < 3; ++g) {
    #pragma unroll
    for (int d = 0; d < D_; d += 2) {
      float o0 = y[d] * gs[g][d] + bs[g][d];
      float o1 = y[d + 1] * gs[g][d + 1] + bs[g][d + 1];
      e[g * N_ * D_ + n * D_ + d] = o0;
      e[g * N_ * D_ + n * D_ + d + 1] = o1;
      *(uint*)&ebf[g * N_ * D_ + n * D_ + d] = packbf(o0, o1);
    }
  }
}

// ---------------------------------------------------------------- fused A_g = softmax(e_g e_g^T, axis=1), bf16
__global__ __launch_bounds__(256)
void k_attn(const ushort* __restrict__ ebf, __hip_bfloat16* __restrict__ A) {
  __shared__ __align__(16) ushort eb[N_ * D_];   // 64 KB
  __shared__ float red[4][16];
  const int t = threadIdx.x;
  const ushort* eg = ebf + (size_t)blockIdx.z * (N_ * D_);
  {
    const uint4* src = (const uint4*)eg;
    uint4* dst = (uint4*)eb;
    #pragma unroll
    for (int i = 0; i < 16; ++i) dst[i * 256 + t] = src[i * 256 + t];
  }
  __syncthreads();
  const int lane = t & 63, w = t >> 6;
  const int l15 = lane & 15, q = lane >> 4;
  const int r0 = blockIdx.x * 16;
  s8 rf = {0, 0, 0, 0, 0, 0, 0, 0};
  if (q < 2) rf = *(const s8*)&eb[(r0 + l15) * D_ + q * 8];
  const int c0 = w * 512;
  f4 acc[32];
  #pragma unroll
  for (int tl = 0; tl < 32; ++tl) {
    s8 cf = {0, 0, 0, 0, 0, 0, 0, 0};
    if (q < 2) cf = *(const s8*)&eb[(c0 + tl * 16 + l15) * D_ + q * 8];
    acc[tl] = __builtin_amdgcn_mfma_f32_16x16x32_bf16(cf, rf, (f4)0.0f, 0, 0, 0);
  }
  float m = acc[0][0];
  #pragma unroll
  for (int tl = 0; tl < 32; ++tl) {
    #pragma unroll
    for (int rg = 0; rg < 4; ++rg) m = fmaxf(m, acc[tl][rg]);
  }
  m = fmaxf(m, __shfl_xor(m, 16, 64));
  m = fmaxf(m, __shfl_xor(m, 32, 64));
  if (lane < 16) red[w][l15] = m;
  __syncthreads();
  const float gm = fmaxf(fmaxf(red[0][l15], red[1][l15]), fmaxf(red[2][l15], red[3][l15]));
  __syncthreads();
  float ps = 0.f;
  #pragma unroll
  for (int tl = 0; tl < 32; ++tl) {
    #pragma unroll
    for (int rg = 0; rg < 4; ++rg) {
      float v = __expf(acc[tl][rg] - gm);
      acc[tl][rg] = v;
      ps += v;
    }
  }
  ps += __shfl_xor(ps, 16, 64);
  ps += __shfl_xor(ps, 32, 64);
  if (lane < 16) red[w][l15] = ps;
  __syncthreads();
  const float inv = 1.0f / (red[0][l15] + red[1][l15] + red[2][l15] + red[3][l15]);
  ushort* Ar = (ushort*)A + (size_t)blockIdx.z * ((size_t)N_ * N_) +
               (size_t)(r0 + l15) * N_ + c0 + q * 4;
  #pragma unroll
  for (int tl = 0; tl < 32; ++tl) {
    uint2 pk;
    pk.x = packbf(acc[tl][0] * inv, acc[tl][1] * inv);
    pk.y = packbf(acc[tl][2] * inv, acc[tl][3] * inv);
    *(uint2*)&Ar[tl * 16] = pk;
  }
}

// ---------------------------------------------------------------- X^T[j=b*C+c][m] bf16 via LDS transpose
template <int MODE>  // 0: xs=[x,state]   1: cand=[x, z*state]
__global__ __launch_bounds__(256)
void k_buildX(const float* __restrict__ x, const float* __restrict__ state,
              const __hip_bfloat16* __restrict__ zbuf, __hip_bfloat16* __restrict__ XT) {
  constexpr int LDM = 72;
  __shared__ __align__(16) ushort T[C_ * LDM];
  const int t = threadIdx.x;
  const int m0 = blockIdx.x * 64, b = blockIdx.y;
  const int m = t >> 2, hq = t & 3;
  {
    const float* sp = state + ((size_t)b * N_ + m0 + m) * H_ + hq * 16;
    float sv[16];
    #pragma unroll
    for (int i = 0; i < 16; i += 4) {
      float4 v = *(const float4*)(sp + i);
      sv[i] = v.x; sv[i + 1] = v.y; sv[i + 2] = v.z; sv[i + 3] = v.w;
    }
    if (MODE) {
      const ushort* zp = (const ushort*)zbuf + ((size_t)b * N_ + m0 + m) * H_ + hq * 16;
      uint4 z0 = *(const uint4*)&zp[0], z1 = *(const uint4*)&zp[8];
      uint zw[8] = {z0.x, z0.y, z0.z, z0.w, z1.x, z1.y, z1.z, z1.w};
      #pragma unroll
      for (int i = 0; i < 8; ++i) {
        sv[2 * i]     *= bf2f((ushort)(zw[i] & 0xffffu));
        sv[2 * i + 1] *= bf2f((ushort)(zw[i] >> 16));
      }
    }
    #pragma unroll
    for (int i = 0; i < 16; ++i) T[(DIN + hq * 16 + i) * LDM + m] = f2bf(sv[i]);
    if (t < 64) {
      const float2 xv = *(const float2*)&x[((size_t)b * N_ + m0 + t) * DIN];
      T[0 * LDM + t] = f2bf(xv.x);
      T[1 * LDM + t] = f2bf(xv.y);
    }
  }
  __syncthreads();
  {
    int r = t >> 2, ch = t & 3;
    ushort* dst = (ushort*)XT + (size_t)(b * C_ + r) * N_ + m0 + ch * 16;
    *(uint4*)&dst[0] = *(uint4*)&T[r * LDM + ch * 16];
    *(uint4*)&dst[8] = *(uint4*)&T[r * LDM + ch * 16 + 8];
    if (t < 8) {
      r = 64 + (t >> 2);
      ushort* dst2 = (ushort*)XT + (size_t)(b * C_ + r) * N_ + m0 + ch * 16;
      *(uint4*)&dst2[0] = *(uint4*)&T[r * LDM + ch * 16];
      *(uint4*)&dst2[8] = *(uint4*)&T[r * LDM + ch * 16 + 8];
    }
  }
}

// ---------------------------------------------------------------- Y[r,j] = sum_m A[r,m] XT[j,m]
// R12-exact (measured best): SINGLE barrier per K-tile; 3-buffer distance-2
// prefetch, counted vmcnt(4); T1 XCD swizzle; T2 both-sides swizzle; T5 setprio.
__global__ __launch_bounds__(256)
void k_gemm(const __hip_bfloat16* __restrict__ Abase, size_t astride,
            const __hip_bfloat16* __restrict__ XT,
            __hip_bfloat16* __restrict__ Ybase, size_t ystride) {
  __shared__ __align__(16) ushort At[3][128 * 32];
  __shared__ __align__(16) ushort Xt[3][128 * 32];
  const int t = threadIdx.x;
  const int nwg = gridDim.x * gridDim.y * gridDim.z;   // 1056 or 528, both %8==0
  const int orig = blockIdx.x + gridDim.x * (blockIdx.y + gridDim.y * blockIdx.z);
  const int chunk = nwg >> 3;
  const int swz = (orig & 7) * chunk + (orig >> 3);
  const int bx = swz % gridDim.x;
  const int rest = swz / gridDim.x;
  const int by = rest % gridDim.y;
  const int bz = rest / gridDim.y;
  const int j0 = bx * 128, r0 = by * 128;
  const ushort* Ag = (const ushort*)Abase + (size_t)bz * astride;
  ushort* Y = (ushort*)Ybase + (size_t)bz * ystride;
  const int lane = t & 63, w = t >> 6;
  const int rowa = w * 32 + (lane >> 2);
  const int kc = (((lane & 3) ^ ((lane >> 3) & 3)) * 8);
  const ushort* pA0 = Ag + (size_t)(r0 + rowa) * N_ + kc;
  const ushort* pA1 = pA0 + 16 * N_;
  const ushort* pX0 = (const ushort*)XT + (size_t)(j0 + rowa) * N_ + kc;
  const ushort* pX1 = pX0 + 16 * N_;
  const int l15 = t & 15, q = (t >> 4) & 3;
  const int qs = (q ^ ((l15 >> 1) & 3)) * 8;
  const int wr = (w >> 1) * 64, wc = (w & 1) * 64;
  f4 acc[4][4];
  #pragma unroll
  for (int i = 0; i < 4; ++i)
    #pragma unroll
    for (int jj = 0; jj < 4; ++jj) acc[i][jj] = (f4)0.0f;
  #pragma unroll
  for (int p = 0; p < 2; ++p) {
    GLD16(pA0, &At[p][(w * 32) * 32]);
    GLD16(pA1, &At[p][(w * 32 + 16) * 32]);
    GLD16(pX0, &Xt[p][(w * 32) * 32]);
    GLD16(pX1, &Xt[p][(w * 32 + 16) * 32]);
    pA0 += 32; pA1 += 32; pX0 += 32; pX1 += 32;
  }
  int cur = 0, nx = 2;
  for (int k0 = 0; k0 < N_; k0 += 32) {
    if (k0 + 32 < N_) asm volatile("s_waitcnt vmcnt(4)" ::: "memory");
    else              asm volatile("s_waitcnt vmcnt(0)" ::: "memory");
    __builtin_amdgcn_s_barrier();           // tile-i data visible; tile-(i-1) reads done
    __builtin_amdgcn_sched_barrier(0);
    if (k0 + 64 < N_) {
      GLD16(pA0, &At[nx][(w * 32) * 32]);
      GLD16(pA1, &At[nx][(w * 32 + 16) * 32]);
      GLD16(pX0, &Xt[nx][(w * 32) * 32]);
      GLD16(pX1, &Xt[nx][(w * 32 + 16) * 32]);
      pA0 += 32; pA1 += 32; pX0 += 32; pX1 += 32;
    }
    s8 af[4], bfr[4];
    #pragma unroll
    for (int mi = 0; mi < 4; ++mi)
      af[mi] = *(const s8*)&At[cur][(wr + mi * 16 + l15) * 32 + qs];
    #pragma unroll
    for (int ni = 0; ni < 4; ++ni)
      bfr[ni] = *(const s8*)&Xt[cur][(wc + ni * 16 + l15) * 32 + qs];
    __builtin_amdgcn_s_setprio(1);
    #pragma unroll
    for (int mi = 0; mi < 4; ++mi)
      #pragma unroll
      for (int ni = 0; ni < 4; ++ni)
        acc[mi][ni] = __builtin_amdgcn_mfma_f32_16x16x32_bf16(af[mi], bfr[ni], acc[mi][ni], 0, 0, 0);
    __builtin_amdgcn_s_setprio(0);
    cur = cur == 2 ? 0 : cur + 1;
    nx = nx == 2 ? 0 : nx + 1;
  }
  // C/D: col = lane&15, row = quad*4 + reg  [verified m89/m91]
  #pragma unroll
  for (int mi = 0; mi < 4; ++mi) {
    int rr = r0 + wr + mi * 16 + q * 4;
    #pragma unroll
    for (int ni = 0; ni < 4; ++ni) {
      int cc = j0 + wc + ni * 16 + l15;
      #pragma unroll
      for (int rg = 0; rg < 4; ++rg)
        Y[(size_t)(rr + rg) * CB + cc] = f2bf(acc[mi][ni][rg]);
    }
  }
}

// ---------------------------------------------------------------- Wm[n][o][KIP] bf16 = sum_d e[n,d] Wp[d,ki,o]
// R15: uniform grid y=0..4 (4 kic each) — removes the 2x-work y==3 stragglers.
__global__ __launch_bounds__(256)
void k_wmat(const float* __restrict__ eg, const float* __restrict__ Wp, ushort* __restrict__ Wm) {
  constexpr int TRS = 36;
  __shared__ float Wl[16 * 8 * 64];     // [d][kr][o]  32 KB
  __shared__ ushort Tr[8 * 64 * TRS];   // [n][o][36]
  const int t = threadIdx.x;
  const int n0 = blockIdx.x * 8;
  const int y = blockIdx.y;             // 0..4, 4 kic each (kic 0..19)
  const int o = t & 63, w = t >> 6;
  const int ng = w & 1, krh = (w >> 1) * 4;
  float er[4][16];
  #pragma unroll
  for (int j = 0; j < 4; ++j) {
    const float* ep = eg + (size_t)(n0 + ng * 4 + j) * D_;
    #pragma unroll
    for (int d = 0; d < D_; d += 4) {
      float4 v = *(const float4*)(ep + d);
      er[j][d] = v.x; er[j][d + 1] = v.y; er[j][d + 2] = v.z; er[j][d + 3] = v.w;
    }
  }
  const int kic0 = y * 4;
  for (int kk = 0; kk < 4; ++kk) {
    const int kic = kic0 + kk;
    __syncthreads();
    #pragma unroll
    for (int it = 0; it < 8; ++it) {
      int f = it * 256 + t;
      int d = f >> 7, rem = f & 127, kr = rem >> 4, o4 = rem & 15;
      int ki = kic * 8 + kr;
      float4 v;
      if (ki < KI) v = *(const float4*)&Wp[((size_t)d * KI + ki) * 64 + o4 * 4];
      else { v.x = 0.f; v.y = 0.f; v.z = 0.f; v.w = 0.f; }
      *(float4*)&Wl[f * 4] = v;
    }
    __syncthreads();
    float a[4][4];
    #pragma unroll
    for (int j = 0; j < 4; ++j)
      #pragma unroll
      for (int k = 0; k < 4; ++k) a[j][k] = 0.f;
    for (int d = 0; d < D_; ++d) {
      float w4[4];
      #pragma unroll
      for (int k = 0; k < 4; ++k) w4[k] = Wl[(d * 8 + krh + k) * 64 + o];
      #pragma unroll
      for (int j = 0; j < 4; ++j)
        #pragma unroll
        for (int k = 0; k < 4; ++k) a[j][k] = fmaf(er[j][d], w4[k], a[j][k]);
    }
    #pragma unroll
    for (int j = 0; j < 4; ++j) {
      ushort* tr = &Tr[((ng * 4 + j) * 64 + o) * TRS + kk * 8 + krh];
      *(uint*)&tr[0] = packbf(a[j][0], a[j][1]);
      *(uint*)&tr[2] = packbf(a[j][2], a[j][3]);
    }
  }
  __syncthreads();
  const int k0 = kic0 * 8;
  #pragma unroll
  for (int p = 0; p < 8; ++p) {
    int u = p * 256 + t;
    int nl = u >> 8, oo = (u >> 2) & 63, qq = u & 3;
    const ushort* tr = &Tr[(nl * 64 + oo) * TRS + qq * 8];
    uint2 lo = *(const uint2*)&tr[0];
    uint2 hi = *(const uint2*)&tr[4];
    uint4 vv; vv.x = lo.x; vv.y = lo.y; vv.z = hi.x; vv.w = hi.y;
    *(uint4*)&Wm[((size_t)(n0 + nl) * 64 + oo) * KIP + k0 + qq * 8] = vv;
  }
}

// ---------------------------------------------------------------- per-node einsum via MFMA; B-frags direct from global Wm (R12 version)
template <int MODE>  // 0: sigmoid -> bf16 gate buf ; 1: tanh + GRU combine -> fp32 d_out
__global__ __launch_bounds__(256)
void k_einsum(const float* __restrict__ e, const ushort* __restrict__ Wm, const float* __restrict__ bp,
              const __hip_bfloat16* __restrict__ Y,
              const float* __restrict__ x, const float* __restrict__ state,
              const __hip_bfloat16* __restrict__ zbuf, const __hip_bfloat16* __restrict__ rbuf,
              void* __restrict__ outp) {
  constexpr int LDK = 168;
  constexpr int LDR = 72;
  __shared__ __align__(16) ushort xg[64 * LDK];
  __shared__ __align__(16) ushort res[64 * LDR];
  __shared__ float el[D_];
  __shared__ float bl[64];
  const int n = blockIdx.x, t = threadIdx.x;
  if (t < D_) el[t] = e[n * D_ + t];
  __syncthreads();
  if (t < 64) {
    float s = 0.f;
    #pragma unroll
    for (int d = 0; d < D_; ++d) s += el[d] * bp[d * 64 + t];
    bl[t] = s;
  }
  {
    const int b = t >> 2, j = t & 3;
    const size_t bn = (size_t)b * N_ + n;
    float sv[16];
    const float* sp = state + bn * 64 + j * 16;
    #pragma unroll
    for (int i = 0; i < 16; i += 4) {
      float4 v = *(const float4*)(sp + i);
      sv[i] = v.x; sv[i + 1] = v.y; sv[i + 2] = v.z; sv[i + 3] = v.w;
    }
    if (MODE) {
      const ushort* zp = (const ushort*)zbuf + bn * 64 + j * 16;
      uint4 z0 = *(const uint4*)&zp[0], z1 = *(const uint4*)&zp[8];
      uint zw[8] = {z0.x, z0.y, z0.z, z0.w, z1.x, z1.y, z1.z, z1.w};
      #pragma unroll
      for (int i = 0; i < 8; ++i) {
        sv[2 * i]     *= bf2f((ushort)(zw[i] & 0xffffu));
        sv[2 * i + 1] *= bf2f((ushort)(zw[i] >> 16));
      }
    }
    ushort* xr = &xg[b * LDK + 2 + j * 16];
    #pragma unroll
    for (int i = 0; i < 16; i += 2) {
      uint pk = packbf(sv[i], sv[i + 1]);
      *(uint*)&xr[i] = pk;
    }
    const ushort* yp = (const ushort*)Y + (size_t)n * CB + b * C_ + j * 16;
    uint* xy = (uint*)&xg[b * LDK + 66 + j * 16];
    #pragma unroll
    for (int i = 0; i < 8; ++i) xy[i] = *(const uint*)&yp[2 * i];
    if (j == 0) *(uint*)&xg[b * LDK + 130] = *(const uint*)&yp[64];
    if (t < 64) {
      const float* xp = x + ((size_t)t * N_ + n) * DIN;
      uint pk = packbf(xp[0], xp[1]);
      *(uint*)&xg[t * LDK] = pk;
    }
    ushort* pg = &xg[b * LDK + 132 + j * 7];
    #pragma unroll
    for (int i = 0; i < 7; ++i) pg[i] = 0;
  }
  __syncthreads();
  const int l15 = t & 15, q = (t >> 4) & 3, w = t >> 6;
  const int wm = (w >> 1) * 32, wn = (w & 1) * 32;
  const ushort* Wn = Wm + (size_t)n * (64 * KIP);
  f4 acc[2][2];
  acc[0][0] = acc[0][1] = acc[1][0] = acc[1][1] = (f4)0.0f;
  #pragma unroll
  for (int kk = 0; kk < KIP; kk += 32) {
    s8 af[2], bfr[2];
    #pragma unroll
    for (int mi = 0; mi < 2; ++mi) af[mi] = *(const s8*)&xg[(wm + mi * 16 + l15) * LDK + kk + q * 8];
    #pragma unroll
    for (int ni = 0; ni < 2; ++ni) bfr[ni] = *(const s8*)(Wn + (size_t)(wn + ni * 16 + l15) * KIP + kk + q * 8);
    #pragma unroll
    for (int mi = 0; mi < 2; ++mi)
      #pragma unroll
      for (int ni = 0; ni < 2; ++ni)
        acc[mi][ni] = __builtin_amdgcn_mfma_f32_16x16x32_bf16(af[mi], bfr[ni], acc[mi][ni], 0, 0, 0);
  }
  {
    float bl0 = bl[wn + l15], bl1 = bl[wn + 16 + l15];
    #pragma unroll
    for (int mi = 0; mi < 2; ++mi)
      #pragma unroll
      for (int ni = 0; ni < 2; ++ni) {
        float bb = ni ? bl1 : bl0;
        #pragma unroll
        for (int rg = 0; rg < 4; ++rg) {
          float v = acc[mi][ni][rg] + bb;
          float a;
          if (MODE == 0) a = 1.0f / (1.0f + __expf(-v));
          else           a = 1.0f - 2.0f / (__expf(2.0f * v) + 1.0f);
          res[(wm + mi * 16 + q * 4 + rg) * LDR + (wn + ni * 16 + l15)] = f2bf(a);
        }
      }
  }
  __syncthreads();
  {
    const int b = t >> 2, j = t & 3;
    const size_t gb = ((size_t)b * N_ + n) * 64 + j * 16;
    const ushort* rr = &res[b * LDR + j * 16];
    if (MODE == 0) {
      uint4 v0 = *(const uint4*)&rr[0];
      uint4 v1 = *(const uint4*)&rr[8];
      *(uint4*)((ushort*)outp + gb) = v0;
      *(uint4*)((ushort*)outp + gb + 8) = v1;
    } else {
      float* ob = (float*)outp;
      const float* stp = state + gb;
      const ushort* rp = (const ushort*)rbuf + gb;
      uint4 r0 = *(const uint4*)&rp[0], r1 = *(const uint4*)&rp[8];
      uint rw[8] = {r0.x, r0.y, r0.z, r0.w, r1.x, r1.y, r1.z, r1.w};
      #pragma unroll
      for (int i = 0; i < 16; i += 4) {
        float4 st = *(const float4*)(stp + i);
        float4 ov;
        float rv0 = bf2f((ushort)(rw[i / 2] & 0xffffu));
        float rv1 = bf2f((ushort)(rw[i / 2] >> 16));
        float rv2 = bf2f((ushort)(rw[i / 2 + 1] & 0xffffu));
        float rv3 = bf2f((ushort)(rw[i / 2 + 1] >> 16));
        ov.x = rv0 * st.x + (1.0f - rv0) * bf2f(rr[i]);
        ov.y = rv1 * st.y + (1.0f - rv1) * bf2f(rr[i + 1]);
        ov.z = rv2 * st.z + (1.0f - rv2) * bf2f(rr[i + 2]);
        ov.w = rv3 * st.w + (1.0f - rv3) * bf2f(rr[i + 3]);
        *(float4*)(ob + gb + i) = ov;
      }
    }
  }
}

// ----------------------------------------------------------------
extern "C" void kernel_launch(void* const* d_in, const int* in_sizes, int n_in,
                              void* d_out, int out_size, void* d_ws, size_t ws_size,
                              hipStream_t stream) {
  const float* x     = (const float*)d_in[0];
  const float* state = (const float*)d_in[1];
  const float* node  = (const float*)d_in[2];
  const float* timee = (const float*)d_in[3];
  const float* W_z = (const float*)d_in[4];
  const float* b_z = (const float*)d_in[5];
  const float* g_z = (const float*)d_in[6];
  const float* be_z = (const float*)d_in[7];
  const float* W_r = (const float*)d_in[8];
  const float* b_r = (const float*)d_in[9];
  const float* g_r = (const float*)d_in[10];
  const float* be_r = (const float*)d_in[11];
  const float* W_u = (const float*)d_in[12];
  const float* b_u = (const float*)d_in[13];
  const float* g_u = (const float*)d_in[14];
  const float* be_u = (const float*)d_in[15];

  constexpr size_t NN = (size_t)N_ * N_;
  constexpr size_t ND = (size_t)N_ * D_;
  char* ws = (char*)d_ws;
  float*           e  = (float*)(ws);                        //       0 :    393,216
  __hip_bfloat16*  A  = (__hip_bfloat16*)(ws + 393216);      //  25,165,824
  __hip_bfloat16*  XT = (__hip_bfloat16*)(ws + 25559040);    //  17,301,504
  __hip_bfloat16*  Y  = (__hip_bfloat16*)(ws + 42860544);    //  17,301,504
  __hip_bfloat16*  zb = (__hip_bfloat16*)(ws + 60162048);    //  16,777,216
  __hip_bfloat16*  rb = (__hip_bfloat16*)(ws + 76939264);    //  16,777,216
  ushort*          ebf = (ushort*)(ws + 93716480);           //  196,608 (dead before Wm written)
  ushort*          Wm = (ushort*)(ws + 93716480);            //  41,943,040 (ends 135,659,520)
  __hip_bfloat16*  Yr = (__hip_bfloat16*)(ws + 135659520);   //  17,301,504 (big-ws only)
  const size_t YRD = ((size_t)135659520 - 42860544) / 2;
  const bool big = ws_size >= (size_t)152961024;

  float* out = (float*)d_out;

  k_e<<<8, 256, 0, stream>>>(node, timee, g_z, be_z, g_r, be_r, g_u, be_u, e, ebf);
  k_attn<<<dim3(N_ / 16, 1, 3), 256, 0, stream>>>(ebf, A);
  k_buildX<0><<<dim3(32, 64), 256, 0, stream>>>(x, state, nullptr, XT);

  dim3 ggrid1(CB / 128, N_ / 128, 1);   // 528 blocks (%8==0)
  dim3 ggrid2(CB / 128, N_ / 128, 2);   // fused z+r: 1056 blocks (%8==0)
  dim3 wgrid(N_ / 8, 5);                // 1280 uniform blocks (4 kic each)

  if (big) {
    k_wmat<<<wgrid, 256, 0, stream>>>(e + 0 * ND, W_z, Wm);
    k_gemm<<<ggrid2, 256, 0, stream>>>(A, NN, XT, Y, YRD);                       // z->Y, r->Yr
    k_einsum<0><<<N_, 256, 0, stream>>>(e + 0 * ND, Wm, b_z, Y, x, state, nullptr, nullptr, (void*)zb);
    k_wmat<<<wgrid, 256, 0, stream>>>(e + 1 * ND, W_r, Wm);
    k_einsum<0><<<N_, 256, 0, stream>>>(e + 1 * ND, Wm, b_r, Yr, x, state, nullptr, nullptr, (void*)rb);
  } else {
    k_wmat<<<wgrid, 256, 0, stream>>>(e + 0 * ND, W_z, Wm);
    k_gemm<<<ggrid1, 256, 0, stream>>>(A, 0, XT, Y, 0);
    k_einsum<0><<<N_, 256, 0, stream>>>(e + 0 * ND, Wm, b_z, Y, x, state, nullptr, nullptr, (void*)zb);
    k_wmat<<<wgrid, 256, 0, stream>>>(e + 1 * ND, W_r, Wm);
    k_gemm<<<ggrid1, 256, 0, stream>>>(A + NN, 0, XT, Y, 0);
    k_einsum<0><<<N_, 256, 0, stream>>>(e + 1 * ND, Wm, b_r, Y, x, state, nullptr, nullptr, (void*)rb);
  }
  // gate u: cand = [x, z*state]
  k_buildX<1><<<dim3(32, 64), 256, 0, stream>>>(x, state, zb, XT);
  k_wmat<<<wgrid, 256, 0, stream>>>(e + 2 * ND, W_u, Wm);
  k_gemm<<<ggrid1, 256, 0, stream>>>(A + 2 * NN, 0, XT, Y, 0);
  k_einsum<1><<<N_, 256, 0, stream>>>(e + 2 * ND, Wm, b_u, Y, x, state, zb, rb, (void*)out);
}

// Round 8
// 430.230 us; speedup vs baseline: 1.4343x; 1.1591x over previous
//
#include <hip/hip_runtime.h>
#include <hip/hip_bf16.h>
#include <math.h>

// GRUCell with adaptive-graph GCN on MI355X (gfx950).
// B=64, N=2048, Din=2, H=64, D=16, C=66, O=64.
// R16: k_wmat (LDS-heavy scalar-FMA, ~30us/gate) replaced by MFMA:
//      k_wcvt: Wp -> Wpb[j][16d] bf16 rows (328KB, L2-resident; j=o*KIP+ki,
//              zero rows for ki>=132). Dead-window placement: z->zb, r->rb,
//              u->A_z panel (dead after gemm z).
//      k_wmat3: gridless-LDS MFMA — A-frag = 16 e-rows (K=32, upper half 0,
//              packed in-reg from fp32 e -> no ebf dependency, Wm aliasing OK);
//              20 j-tiles/wave of {coalesced B-frag, mfma, 4 stores}.
//      Output map (k_gemm/k_attn-verified): A-row(node)->q*4+rg, B-row(j)->l15.
//      k_gemm stays R12-exact (pinned 109-114us plateau). einsum unchanged.

typedef __attribute__((ext_vector_type(4))) float f4;
typedef __attribute__((ext_vector_type(8))) short s8;  // 8 bf16 in 4 VGPRs (MFMA A/B frag)

#define B_   64
#define N_   2048
#define DIN  2
#define H_   64
#define D_   16
#define C_   66    // DIN + H
#define KI   132   // 2*C
#define KIP  160   // KI padded for K-loop (multiple of 32)
#define CB   4224  // B_*C_
#define JW   10240 // 64*KIP — Wm row length (j = o*KIP + ki)

#define GLD16(gp, lp) __builtin_amdgcn_global_load_lds((const __attribute__((address_space(1))) void*)(gp), (__attribute__((address_space(3))) void*)(lp), 16, 0, 0)

static __device__ __forceinline__ ushort f2bf(float v) {
  __hip_bfloat16 h = __float2bfloat16(v);
  return *(ushort*)&h;
}
static __device__ __forceinline__ float bf2f(ushort u) {
  __hip_bfloat16 h = *(__hip_bfloat16*)&u;
  return __bfloat162float(h);
}
static __device__ __forceinline__ uint packbf(float a, float b) {
  return ((uint)f2bf(b) << 16) | f2bf(a);
}

// ---------------------------------------------------------------- e = LN(node+time)*gamma+beta (fp32 + bf16 copies)
__global__ void k_e(const float* __restrict__ node, const float* __restrict__ timee,
                    const float* __restrict__ g0, const float* __restrict__ b0,
                    const float* __restrict__ g1, const float* __restrict__ b1,
                    const float* __restrict__ g2, const float* __restrict__ b2,
                    float* __restrict__ e, ushort* __restrict__ ebf) {
  int n = blockIdx.x * blockDim.x + threadIdx.x;
  if (n >= N_) return;
  float v[D_]; float m = 0.f;
  #pragma unroll
  for (int d = 0; d < D_; ++d) { v[d] = node[n * D_ + d] + timee[d]; m += v[d]; }
  m *= (1.0f / D_);
  float var = 0.f;
  #pragma unroll
  for (int d = 0; d < D_; ++d) { float t = v[d] - m; var += t * t; }
  var *= (1.0f / D_);
  float r = rsqrtf(var + 1e-12f);
  float y[D_];
  #pragma unroll
  for (int d = 0; d < D_; ++d) y[d] = (v[d] - m) * r;
  const float* gs[3] = {g0, g1, g2};
  const float* bs[3] = {b0, b1, b2};
  #pragma unroll
  for (int g = 0; g < 3; ++g) {
    #pragma unroll
    for (int d = 0; d < D_; d += 2) {
      float o0 = y[d] * gs[g][d] + bs[g][d];
      float o1 = y[d + 1] * gs[g][d + 1] + bs[g][d + 1];
      e[g * N_ * D_ + n * D_ + d] = o0;
      e[g * N_ * D_ + n * D_ + d + 1] = o1;
      *(uint*)&ebf[g * N_ * D_ + n * D_ + d] = packbf(o0, o1);
    }
  }
}

// ---------------------------------------------------------------- fused A_g = softmax(e_g e_g^T, axis=1), bf16
__global__ __launch_bounds__(256)
void k_attn(const ushort* __restrict__ ebf, __hip_bfloat16* __restrict__ A) {
  __shared__ __align__(16) ushort eb[N_ * D_];   // 64 KB
  __shared__ float red[4][16];
  const int t = threadIdx.x;
  const ushort* eg = ebf + (size_t)blockIdx.z * (N_ * D_);
  {
    const uint4* src = (const uint4*)eg;
    uint4* dst = (uint4*)eb;
    #pragma unroll
    for (int i = 0; i < 16; ++i) dst[i * 256 + t] = src[i * 256 + t];
  }
  __syncthreads();
  const int lane = t & 63, w = t >> 6;
  const int l15 = lane & 15, q = lane >> 4;
  const int r0 = blockIdx.x * 16;
  s8 rf = {0, 0, 0, 0, 0, 0, 0, 0};
  if (q < 2) rf = *(const s8*)&eb[(r0 + l15) * D_ + q * 8];
  const int c0 = w * 512;
  f4 acc[32];
  #pragma unroll
  for (int tl = 0; tl < 32; ++tl) {
    s8 cf = {0, 0, 0, 0, 0, 0, 0, 0};
    if (q < 2) cf = *(const s8*)&eb[(c0 + tl * 16 + l15) * D_ + q * 8];
    acc[tl] = __builtin_amdgcn_mfma_f32_16x16x32_bf16(cf, rf, (f4)0.0f, 0, 0, 0);
  }
  float m = acc[0][0];
  #pragma unroll
  for (int tl = 0; tl < 32; ++tl) {
    #pragma unroll
    for (int rg = 0; rg < 4; ++rg) m = fmaxf(m, acc[tl][rg]);
  }
  m = fmaxf(m, __shfl_xor(m, 16, 64));
  m = fmaxf(m, __shfl_xor(m, 32, 64));
  if (lane < 16) red[w][l15] = m;
  __syncthreads();
  const float gm = fmaxf(fmaxf(red[0][l15], red[1][l15]), fmaxf(red[2][l15], red[3][l15]));
  __syncthreads();
  float ps = 0.f;
  #pragma unroll
  for (int tl = 0; tl < 32; ++tl) {
    #pragma unroll
    for (int rg = 0; rg < 4; ++rg) {
      float v = __expf(acc[tl][rg] - gm);
      acc[tl][rg] = v;
      ps += v;
    }
  }
  ps += __shfl_xor(ps, 16, 64);
  ps += __shfl_xor(ps, 32, 64);
  if (lane < 16) red[w][l15] = ps;
  __syncthreads();
  const float inv = 1.0f / (red[0][l15] + red[1][l15] + red[2][l15] + red[3][l15]);
  ushort* Ar = (ushort*)A + (size_t)blockIdx.z * ((size_t)N_ * N_) +
               (size_t)(r0 + l15) * N_ + c0 + q * 4;
  #pragma unroll
  for (int tl = 0; tl < 32; ++tl) {
    uint2 pk;
    pk.x = packbf(acc[tl][0] * inv, acc[tl][1] * inv);
    pk.y = packbf(acc[tl][2] * inv, acc[tl][3] * inv);
    *(uint2*)&Ar[tl * 16] = pk;
  }
}

// ---------------------------------------------------------------- X^T[j=b*C+c][m] bf16 via LDS transpose
template <int MODE>  // 0: xs=[x,state]   1: cand=[x, z*state]
__global__ __launch_bounds__(256)
void k_buildX(const float* __restrict__ x, const float* __restrict__ state,
              const __hip_bfloat16* __restrict__ zbuf, __hip_bfloat16* __restrict__ XT) {
  constexpr int LDM = 72;
  __shared__ __align__(16) ushort T[C_ * LDM];
  const int t = threadIdx.x;
  const int m0 = blockIdx.x * 64, b = blockIdx.y;
  const int m = t >> 2, hq = t & 3;
  {
    const float* sp = state + ((size_t)b * N_ + m0 + m) * H_ + hq * 16;
    float sv[16];
    #pragma unroll
    for (int i = 0; i < 16; i += 4) {
      float4 v = *(const float4*)(sp + i);
      sv[i] = v.x; sv[i + 1] = v.y; sv[i + 2] = v.z; sv[i + 3] = v.w;
    }
    if (MODE) {
      const ushort* zp = (const ushort*)zbuf + ((size_t)b * N_ + m0 + m) * H_ + hq * 16;
      uint4 z0 = *(const uint4*)&zp[0], z1 = *(const uint4*)&zp[8];
      uint zw[8] = {z0.x, z0.y, z0.z, z0.w, z1.x, z1.y, z1.z, z1.w};
      #pragma unroll
      for (int i = 0; i < 8; ++i) {
        sv[2 * i]     *= bf2f((ushort)(zw[i] & 0xffffu));
        sv[2 * i + 1] *= bf2f((ushort)(zw[i] >> 16));
      }
    }
    #pragma unroll
    for (int i = 0; i < 16; ++i) T[(DIN + hq * 16 + i) * LDM + m] = f2bf(sv[i]);
    if (t < 64) {
      const float2 xv = *(const float2*)&x[((size_t)b * N_ + m0 + t) * DIN];
      T[0 * LDM + t] = f2bf(xv.x);
      T[1 * LDM + t] = f2bf(xv.y);
    }
  }
  __syncthreads();
  {
    int r = t >> 2, ch = t & 3;
    ushort* dst = (ushort*)XT + (size_t)(b * C_ + r) * N_ + m0 + ch * 16;
    *(uint4*)&dst[0] = *(uint4*)&T[r * LDM + ch * 16];
    *(uint4*)&dst[8] = *(uint4*)&T[r * LDM + ch * 16 + 8];
    if (t < 8) {
      r = 64 + (t >> 2);
      ushort* dst2 = (ushort*)XT + (size_t)(b * C_ + r) * N_ + m0 + ch * 16;
      *(uint4*)&dst2[0] = *(uint4*)&T[r * LDM + ch * 16];
      *(uint4*)&dst2[8] = *(uint4*)&T[r * LDM + ch * 16 + 8];
    }
  }
}

// ---------------------------------------------------------------- Y[r,j] = sum_m A[r,m] XT[j,m]
// R12-exact (measured best): SINGLE barrier per K-tile; 3-buffer distance-2
// prefetch, counted vmcnt(4); T1 XCD swizzle; T2 both-sides swizzle; T5 setprio.
__global__ __launch_bounds__(256)
void k_gemm(const __hip_bfloat16* __restrict__ Abase, size_t astride,
            const __hip_bfloat16* __restrict__ XT,
            __hip_bfloat16* __restrict__ Ybase, size_t ystride) {
  __shared__ __align__(16) ushort At[3][128 * 32];
  __shared__ __align__(16) ushort Xt[3][128 * 32];
  const int t = threadIdx.x;
  const int nwg = gridDim.x * gridDim.y * gridDim.z;   // 1056 or 528, both %8==0
  const int orig = blockIdx.x + gridDim.x * (blockIdx.y + gridDim.y * blockIdx.z);
  const int chunk = nwg >> 3;
  const int swz = (orig & 7) * chunk + (orig >> 3);
  const int bx = swz % gridDim.x;
  const int rest = swz / gridDim.x;
  const int by = rest % gridDim.y;
  const int bz = rest / gridDim.y;
  const int j0 = bx * 128, r0 = by * 128;
  const ushort* Ag = (const ushort*)Abase + (size_t)bz * astride;
  ushort* Y = (ushort*)Ybase + (size_t)bz * ystride;
  const int lane = t & 63, w = t >> 6;
  const int rowa = w * 32 + (lane >> 2);
  const int kc = (((lane & 3) ^ ((lane >> 3) & 3)) * 8);
  const ushort* pA0 = Ag + (size_t)(r0 + rowa) * N_ + kc;
  const ushort* pA1 = pA0 + 16 * N_;
  const ushort* pX0 = (const ushort*)XT + (size_t)(j0 + rowa) * N_ + kc;
  const ushort* pX1 = pX0 + 16 * N_;
  const int l15 = t & 15, q = (t >> 4) & 3;
  const int qs = (q ^ ((l15 >> 1) & 3)) * 8;
  const int wr = (w >> 1) * 64, wc = (w & 1) * 64;
  f4 acc[4][4];
  #pragma unroll
  for (int i = 0; i < 4; ++i)
    #pragma unroll
    for (int jj = 0; jj < 4; ++jj) acc[i][jj] = (f4)0.0f;
  #pragma unroll
  for (int p = 0; p < 2; ++p) {
    GLD16(pA0, &At[p][(w * 32) * 32]);
    GLD16(pA1, &At[p][(w * 32 + 16) * 32]);
    GLD16(pX0, &Xt[p][(w * 32) * 32]);
    GLD16(pX1, &Xt[p][(w * 32 + 16) * 32]);
    pA0 += 32; pA1 += 32; pX0 += 32; pX1 += 32;
  }
  int cur = 0, nx = 2;
  for (int k0 = 0; k0 < N_; k0 += 32) {
    if (k0 + 32 < N_) asm volatile("s_waitcnt vmcnt(4)" ::: "memory");
    else              asm volatile("s_waitcnt vmcnt(0)" ::: "memory");
    __builtin_amdgcn_s_barrier();           // tile-i data visible; tile-(i-1) reads done
    __builtin_amdgcn_sched_barrier(0);
    if (k0 + 64 < N_) {
      GLD16(pA0, &At[nx][(w * 32) * 32]);
      GLD16(pA1, &At[nx][(w * 32 + 16) * 32]);
      GLD16(pX0, &Xt[nx][(w * 32) * 32]);
      GLD16(pX1, &Xt[nx][(w * 32 + 16) * 32]);
      pA0 += 32; pA1 += 32; pX0 += 32; pX1 += 32;
    }
    s8 af[4], bfr[4];
    #pragma unroll
    for (int mi = 0; mi < 4; ++mi)
      af[mi] = *(const s8*)&At[cur][(wr + mi * 16 + l15) * 32 + qs];
    #pragma unroll
    for (int ni = 0; ni < 4; ++ni)
      bfr[ni] = *(const s8*)&Xt[cur][(wc + ni * 16 + l15) * 32 + qs];
    __builtin_amdgcn_s_setprio(1);
    #pragma unroll
    for (int mi = 0; mi < 4; ++mi)
      #pragma unroll
      for (int ni = 0; ni < 4; ++ni)
        acc[mi][ni] = __builtin_amdgcn_mfma_f32_16x16x32_bf16(af[mi], bfr[ni], acc[mi][ni], 0, 0, 0);
    __builtin_amdgcn_s_setprio(0);
    cur = cur == 2 ? 0 : cur + 1;
    nx = nx == 2 ? 0 : nx + 1;
  }
  // C/D: col = lane&15, row = quad*4 + reg  [verified m89/m91]
  #pragma unroll
  for (int mi = 0; mi < 4; ++mi) {
    int rr = r0 + wr + mi * 16 + q * 4;
    #pragma unroll
    for (int ni = 0; ni < 4; ++ni) {
      int cc = j0 + wc + ni * 16 + l15;
      #pragma unroll
      for (int rg = 0; rg < 4; ++rg)
        Y[(size_t)(rr + rg) * CB + cc] = f2bf(acc[mi][ni][rg]);
    }
  }
}

// ---------------------------------------------------------------- Wpb[j][16] bf16 = Wp[d][ki][o] transposed; j = o*KIP+ki, zero rows ki>=132
__global__ void k_wcvt(const float* __restrict__ Wp, ushort* __restrict__ Wpb) {
  int j = blockIdx.x * 256 + threadIdx.x;   // 40 blocks x 256 = 10240
  if (j >= JW) return;
  int o = j / KIP, ki = j - o * KIP;
  ushort row[16];
  #pragma unroll
  for (int d = 0; d < 16; ++d) row[d] = 0;
  if (ki < KI) {
    #pragma unroll
    for (int d = 0; d < 16; ++d) row[d] = f2bf(Wp[((size_t)d * KI + ki) * 64 + o]);
  }
  *(uint4*)&Wpb[(size_t)j * 16] = *(uint4*)&row[0];
  *(uint4*)&Wpb[(size_t)j * 16 + 8] = *(uint4*)&row[8];
}

// ---------------------------------------------------------------- Wm[n][j] bf16 = sum_d e[n,d] Wpb[j][d] via MFMA
// No LDS, no barriers. A-frag: 16 e-rows (K=32, upper half zero; packed in-reg
// from fp32 e). B-frag: 16 Wpb rows (32B each, coalesced, L2-resident).
// Output map (verified k_gemm/k_attn): node -> q*4+rg, j -> l15.
__global__ __launch_bounds__(256)
void k_wmat3(const float* __restrict__ eg, const ushort* __restrict__ Wpb, ushort* __restrict__ Wm) {
  const int t = threadIdx.x;
  const int lane = t & 63, w = t >> 6;
  const int l15 = lane & 15, q = lane >> 4;
  const int n0 = blockIdx.x * 16;
  s8 af = {0, 0, 0, 0, 0, 0, 0, 0};
  if (q < 2) {
    const float* ep = eg + (size_t)(n0 + l15) * D_ + q * 8;
    float4 v0 = *(const float4*)ep, v1 = *(const float4*)(ep + 4);
    ushort pk[8] = {f2bf(v0.x), f2bf(v0.y), f2bf(v0.z), f2bf(v0.w),
                    f2bf(v1.x), f2bf(v1.y), f2bf(v1.z), f2bf(v1.w)};
    af = *(const s8*)pk;
  }
  const int jt0 = blockIdx.y * 80 + w * 20;   // 640 j-tiles / 8 y-blocks / 4 waves
  ushort* wbase = Wm + (size_t)(n0 + q * 4) * JW;
  #pragma unroll 4
  for (int i = 0; i < 20; ++i) {
    const int jt = jt0 + i;
    s8 bfr = {0, 0, 0, 0, 0, 0, 0, 0};
    if (q < 2) bfr = *(const s8*)&Wpb[(size_t)(jt * 16 + l15) * 16 + q * 8];
    f4 acc = __builtin_amdgcn_mfma_f32_16x16x32_bf16(af, bfr, (f4)0.0f, 0, 0, 0);
    const int col = jt * 16 + l15;
    #pragma unroll
    for (int rg = 0; rg < 4; ++rg)
      wbase[(size_t)rg * JW + col] = f2bf(acc[rg]);
  }
}

// ---------------------------------------------------------------- per-node einsum via MFMA; B-frags direct from global Wm
template <int MODE>  // 0: sigmoid -> bf16 gate buf ; 1: tanh + GRU combine -> fp32 d_out
__global__ __launch_bounds__(256)
void k_einsum(const float* __restrict__ e, const ushort* __restrict__ Wm, const float* __restrict__ bp,
              const __hip_bfloat16* __restrict__ Y,
              const float* __restrict__ x, const float* __restrict__ state,
              const __hip_bfloat16* __restrict__ zbuf, const __hip_bfloat16* __restrict__ rbuf,
              void* __restrict__ outp) {
  constexpr int LDK = 168;
  constexpr int LDR = 72;
  __shared__ __align__(16) ushort xg[64 * LDK];
  __shared__ __align__(16) ushort res[64 * LDR];
  __shared__ float el[D_];
  __shared__ float bl[64];
  const int n = blockIdx.x, t = threadIdx.x;
  if (t < D_) el[t] = e[n * D_ + t];
  __syncthreads();
  if (t < 64) {
    float s = 0.f;
    #pragma unroll
    for (int d = 0; d < D_; ++d) s += el[d] * bp[d * 64 + t];
    bl[t] = s;
  }
  {
    const int b = t >> 2, j = t & 3;
    const size_t bn = (size_t)b * N_ + n;
    float sv[16];
    const float* sp = state + bn * 64 + j * 16;
    #pragma unroll
    for (int i = 0; i < 16; i += 4) {
      float4 v = *(const float4*)(sp + i);
      sv[i] = v.x; sv[i + 1] = v.y; sv[i + 2] = v.z; sv[i + 3] = v.w;
    }
    if (MODE) {
      const ushort* zp = (const ushort*)zbuf + bn * 64 + j * 16;
      uint4 z0 = *(const uint4*)&zp[0], z1 = *(const uint4*)&zp[8];
      uint zw[8] = {z0.x, z0.y, z0.z, z0.w, z1.x, z1.y, z1.z, z1.w};
      #pragma unroll
      for (int i = 0; i < 8; ++i) {
        sv[2 * i]     *= bf2f((ushort)(zw[i] & 0xffffu));
        sv[2 * i + 1] *= bf2f((ushort)(zw[i] >> 16));
      }
    }
    ushort* xr = &xg[b * LDK + 2 + j * 16];
    #pragma unroll
    for (int i = 0; i < 16; i += 2) {
      uint pk = packbf(sv[i], sv[i + 1]);
      *(uint*)&xr[i] = pk;
    }
    const ushort* yp = (const ushort*)Y + (size_t)n * CB + b * C_ + j * 16;
    uint* xy = (uint*)&xg[b * LDK + 66 + j * 16];
    #pragma unroll
    for (int i = 0; i < 8; ++i) xy[i] = *(const uint*)&yp[2 * i];
    if (j == 0) *(uint*)&xg[b * LDK + 130] = *(const uint*)&yp[64];
    if (t < 64) {
      const float* xp = x + ((size_t)t * N_ + n) * DIN;
      uint pk = packbf(xp[0], xp[1]);
      *(uint*)&xg[t * LDK] = pk;
    }
    ushort* pg = &xg[b * LDK + 132 + j * 7];
    #pragma unroll
    for (int i = 0; i < 7; ++i) pg[i] = 0;
  }
  __syncthreads();
  const int l15 = t & 15, q = (t >> 4) & 3, w = t >> 6;
  const int wm = (w >> 1) * 32, wn = (w & 1) * 32;
  const ushort* Wn = Wm + (size_t)n * (64 * KIP);
  f4 acc[2][2];
  acc[0][0] = acc[0][1] = acc[1][0] = acc[1][1] = (f4)0.0f;
  #pragma unroll
  for (int kk = 0; kk < KIP; kk += 32) {
    s8 af[2], bfr[2];
    #pragma unroll
    for (int mi = 0; mi < 2; ++mi) af[mi] = *(const s8*)&xg[(wm + mi * 16 + l15) * LDK + kk + q * 8];
    #pragma unroll
    for (int ni = 0; ni < 2; ++ni) bfr[ni] = *(const s8*)(Wn + (size_t)(wn + ni * 16 + l15) * KIP + kk + q * 8);
    #pragma unroll
    for (int mi = 0; mi < 2; ++mi)
      #pragma unroll
      for (int ni = 0; ni < 2; ++ni)
        acc[mi][ni] = __builtin_amdgcn_mfma_f32_16x16x32_bf16(af[mi], bfr[ni], acc[mi][ni], 0, 0, 0);
  }
  {
    float bl0 = bl[wn + l15], bl1 = bl[wn + 16 + l15];
    #pragma unroll
    for (int mi = 0; mi < 2; ++mi)
      #pragma unroll
      for (int ni = 0; ni < 2; ++ni) {
        float bb = ni ? bl1 : bl0;
        #pragma unroll
        for (int rg = 0; rg < 4; ++rg) {
          float v = acc[mi][ni][rg] + bb;
          float a;
          if (MODE == 0) a = 1.0f / (1.0f + __expf(-v));
          else           a = 1.0f - 2.0f / (__expf(2.0f * v) + 1.0f);
          res[(wm + mi * 16 + q * 4 + rg) * LDR + (wn + ni * 16 + l15)] = f2bf(a);
        }
      }
  }
  __syncthreads();
  {
    const int b = t >> 2, j = t & 3;
    const size_t gb = ((size_t)b * N_ + n) * 64 + j * 16;
    const ushort* rr = &res[b * LDR + j * 16];
    if (MODE == 0) {
      uint4 v0 = *(const uint4*)&rr[0];
      uint4 v1 = *(const uint4*)&rr[8];
      *(uint4*)((ushort*)outp + gb) = v0;
      *(uint4*)((ushort*)outp + gb + 8) = v1;
    } else {
      float* ob = (float*)outp;
      const float* stp = state + gb;
      const ushort* rp = (const ushort*)rbuf + gb;
      uint4 r0 = *(const uint4*)&rp[0], r1 = *(const uint4*)&rp[8];
      uint rw[8] = {r0.x, r0.y, r0.z, r0.w, r1.x, r1.y, r1.z, r1.w};
      #pragma unroll
      for (int i = 0; i < 16; i += 4) {
        float4 st = *(const float4*)(stp + i);
        float4 ov;
        float rv0 = bf2f((ushort)(rw[i / 2] & 0xffffu));
        float rv1 = bf2f((ushort)(rw[i / 2] >> 16));
        float rv2 = bf2f((ushort)(rw[i / 2 + 1] & 0xffffu));
        float rv3 = bf2f((ushort)(rw[i / 2 + 1] >> 16));
        ov.x = rv0 * st.x + (1.0f - rv0) * bf2f(rr[i]);
        ov.y = rv1 * st.y + (1.0f - rv1) * bf2f(rr[i + 1]);
        ov.z = rv2 * st.z + (1.0f - rv2) * bf2f(rr[i + 2]);
        ov.w = rv3 * st.w + (1.0f - rv3) * bf2f(rr[i + 3]);
        *(float4*)(ob + gb + i) = ov;
      }
    }
  }
}

// ----------------------------------------------------------------
extern "C" void kernel_launch(void* const* d_in, const int* in_sizes, int n_in,
                              void* d_out, int out_size, void* d_ws, size_t ws_size,
                              hipStream_t stream) {
  const float* x     = (const float*)d_in[0];
  const float* state = (const float*)d_in[1];
  const float* node  = (const float*)d_in[2];
  const float* timee = (const float*)d_in[3];
  const float* W_z = (const float*)d_in[4];
  const float* b_z = (const float*)d_in[5];
  const float* g_z = (const float*)d_in[6];
  const float* be_z = (const float*)d_in[7];
  const float* W_r = (const float*)d_in[8];
  const float* b_r = (const float*)d_in[9];
  const float* g_r = (const float*)d_in[10];
  const float* be_r = (const float*)d_in[11];
  const float* W_u = (const float*)d_in[12];
  const float* b_u = (const float*)d_in[13];
  const float* g_u = (const float*)d_in[14];
  const float* be_u = (const float*)d_in[15];

  constexpr size_t NN = (size_t)N_ * N_;
  constexpr size_t ND = (size_t)N_ * D_;
  char* ws = (char*)d_ws;
  float*           e  = (float*)(ws);                        //       0 :    393,216
  __hip_bfloat16*  A  = (__hip_bfloat16*)(ws + 393216);      //  25,165,824
  __hip_bfloat16*  XT = (__hip_bfloat16*)(ws + 25559040);    //  17,301,504
  __hip_bfloat16*  Y  = (__hip_bfloat16*)(ws + 42860544);    //  17,301,504
  __hip_bfloat16*  zb = (__hip_bfloat16*)(ws + 60162048);    //  16,777,216
  __hip_bfloat16*  rb = (__hip_bfloat16*)(ws + 76939264);    //  16,777,216
  ushort*          ebf = (ushort*)(ws + 93716480);           //  196,608 (dead before Wm written)
  ushort*          Wm = (ushort*)(ws + 93716480);            //  41,943,040 (ends 135,659,520)
  __hip_bfloat16*  Yr = (__hip_bfloat16*)(ws + 135659520);   //  17,301,504 (big-ws only)
  const size_t YRD = ((size_t)135659520 - 42860544) / 2;
  const bool big = ws_size >= (size_t)152961024;
  // Wpb scratch (327,680 B) in provably-dead windows:
  //  z: zb base (einsum z writes zb AFTER wmat3 z consumed Wpb_z)
  //  r: rb base (einsum r writes rb AFTER wmat3 r consumed Wpb_r)
  //  u: A_z panel base (dead after the z(+r) GEMM; wcvt u runs after einsum r)
  ushort* Wpb_z = (ushort*)(ws + 60162048);
  ushort* Wpb_r = (ushort*)(ws + 76939264);
  ushort* Wpb_u = (ushort*)(ws + 393216);

  float* out = (float*)d_out;

  k_e<<<8, 256, 0, stream>>>(node, timee, g_z, be_z, g_r, be_r, g_u, be_u, e, ebf);
  k_attn<<<dim3(N_ / 16, 1, 3), 256, 0, stream>>>(ebf, A);
  k_buildX<0><<<dim3(32, 64), 256, 0, stream>>>(x, state, nullptr, XT);

  dim3 ggrid1(CB / 128, N_ / 128, 1);   // 528 blocks (%8==0)
  dim3 ggrid2(CB / 128, N_ / 128, 2);   // fused z+r: 1056 blocks (%8==0)
  dim3 wgrid3(N_ / 16, 8);              // k_wmat3: 1024 blocks

  if (big) {
    k_wcvt<<<40, 256, 0, stream>>>(W_z, Wpb_z);
    k_wmat3<<<wgrid3, 256, 0, stream>>>(e + 0 * ND, Wpb_z, Wm);
    k_gemm<<<ggrid2, 256, 0, stream>>>(A, NN, XT, Y, YRD);                       // z->Y, r->Yr
    k_einsum<0><<<N_, 256, 0, stream>>>(e + 0 * ND, Wm, b_z, Y, x, state, nullptr, nullptr, (void*)zb);
    k_wcvt<<<40, 256, 0, stream>>>(W_r, Wpb_r);
    k_wmat3<<<wgrid3, 256, 0, stream>>>(e + 1 * ND, Wpb_r, Wm);
    k_einsum<0><<<N_, 256, 0, stream>>>(e + 1 * ND, Wm, b_r, Yr, x, state, nullptr, nullptr, (void*)rb);
  } else {
    k_wcvt<<<40, 256, 0, stream>>>(W_z, Wpb_z);
    k_wmat3<<<wgrid3, 256, 0, stream>>>(e + 0 * ND, Wpb_z, Wm);
    k_gemm<<<ggrid1, 256, 0, stream>>>(A, 0, XT, Y, 0);
    k_einsum<0><<<N_, 256, 0, stream>>>(e + 0 * ND, Wm, b_z, Y, x, state, nullptr, nullptr, (void*)zb);
    k_wcvt<<<40, 256, 0, stream>>>(W_r, Wpb_r);
    k_wmat3<<<wgrid3, 256, 0, stream>>>(e + 1 * ND, Wpb_r, Wm);
    k_gemm<<<ggrid1, 256, 0, stream>>>(A + NN, 0, XT, Y, 0);
    k_einsum<0><<<N_, 256, 0, stream>>>(e + 1 * ND, Wm, b_r, Y, x, state, nullptr, nullptr, (void*)rb);
  }
  // gate u: cand = [x, z*state]
  k_buildX<1><<<dim3(32, 64), 256, 0, stream>>>(x, state, zb, XT);
  k_wcvt<<<40, 256, 0, stream>>>(W_u, Wpb_u);               // A_z panel dead by now
  k_wmat3<<<wgrid3, 256, 0, stream>>>(e + 2 * ND, Wpb_u, Wm);
  k_gemm<<<ggrid1, 256, 0, stream>>>(A + 2 * NN, 0, XT, Y, 0);
  k_einsum<1><<<N_, 256, 0, stream>>>(e + 2 * ND, Wm, b_u, Y, x, state, zb, rb, (void*)out);
}

// Round 9
// 422.678 us; speedup vs baseline: 1.4599x; 1.0179x over previous
//
#include <hip/hip_runtime.h>
#include <hip/hip_bf16.h>
#include <math.h>

// GRUCell with adaptive-graph GCN on MI355X (gfx950).
// B=64, N=2048, Din=2, H=64, D=16, C=66, O=64.
// R17: Wm stored in FRAGMENT ORDER — Wmf[n][ks=ki/32][o][ki%32] — so k_einsum's
//      B-frag loads are fully coalesced (wave reads one contiguous 1KB block,
//      16 lines, vs 320B-stride gather touching 16 lines PER LANE GROUP).
//      Same bytes, bit-identical arithmetic. wmat3 store side restructured to
//      compile-time (oo,s) loops (jt0 % 10 == 0 always). einsum: el[] staging
//      + first barrier dropped (bl reads e via L1 broadcast). wcvt z+r merged
//      into one dispatch. k_gemm stays R12-exact (pinned plateau).

typedef __attribute__((ext_vector_type(4))) float f4;
typedef __attribute__((ext_vector_type(8))) short s8;  // 8 bf16 in 4 VGPRs (MFMA A/B frag)

#define B_   64
#define N_   2048
#define DIN  2
#define H_   64
#define D_   16
#define C_   66    // DIN + H
#define KI   132   // 2*C
#define KIP  160   // KI padded for K-loop (multiple of 32)
#define CB   4224  // B_*C_
#define JW   10240 // Wm row length per node (5 ks-planes x 64 o x 32)

#define GLD16(gp, lp) __builtin_amdgcn_global_load_lds((const __attribute__((address_space(1))) void*)(gp), (__attribute__((address_space(3))) void*)(lp), 16, 0, 0)

static __device__ __forceinline__ ushort f2bf(float v) {
  __hip_bfloat16 h = __float2bfloat16(v);
  return *(ushort*)&h;
}
static __device__ __forceinline__ float bf2f(ushort u) {
  __hip_bfloat16 h = *(__hip_bfloat16*)&u;
  return __bfloat162float(h);
}
static __device__ __forceinline__ uint packbf(float a, float b) {
  return ((uint)f2bf(b) << 16) | f2bf(a);
}

// ---------------------------------------------------------------- e = LN(node+time)*gamma+beta (fp32 + bf16 copies)
__global__ void k_e(const float* __restrict__ node, const float* __restrict__ timee,
                    const float* __restrict__ g0, const float* __restrict__ b0,
                    const float* __restrict__ g1, const float* __restrict__ b1,
                    const float* __restrict__ g2, const float* __restrict__ b2,
                    float* __restrict__ e, ushort* __restrict__ ebf) {
  int n = blockIdx.x * blockDim.x + threadIdx.x;
  if (n >= N_) return;
  float v[D_]; float m = 0.f;
  #pragma unroll
  for (int d = 0; d < D_; ++d) { v[d] = node[n * D_ + d] + timee[d]; m += v[d]; }
  m *= (1.0f / D_);
  float var = 0.f;
  #pragma unroll
  for (int d = 0; d < D_; ++d) { float t = v[d] - m; var += t * t; }
  var *= (1.0f / D_);
  float r = rsqrtf(var + 1e-12f);
  float y[D_];
  #pragma unroll
  for (int d = 0; d < D_; ++d) y[d] = (v[d] - m) * r;
  const float* gs[3] = {g0, g1, g2};
  const float* bs[3] = {b0, b1, b2};
  #pragma unroll
  for (int g = 0; g < 3; ++g) {
    #pragma unroll
    for (int d = 0; d < D_; d += 2) {
      float o0 = y[d] * gs[g][d] + bs[g][d];
      float o1 = y[d + 1] * gs[g][d + 1] + bs[g][d + 1];
      e[g * N_ * D_ + n * D_ + d] = o0;
      e[g * N_ * D_ + n * D_ + d + 1] = o1;
      *(uint*)&ebf[g * N_ * D_ + n * D_ + d] = packbf(o0, o1);
    }
  }
}

// ---------------------------------------------------------------- fused A_g = softmax(e_g e_g^T, axis=1), bf16
__global__ __launch_bounds__(256)
void k_attn(const ushort* __restrict__ ebf, __hip_bfloat16* __restrict__ A) {
  __shared__ __align__(16) ushort eb[N_ * D_];   // 64 KB
  __shared__ float red[4][16];
  const int t = threadIdx.x;
  const ushort* eg = ebf + (size_t)blockIdx.z * (N_ * D_);
  {
    const uint4* src = (const uint4*)eg;
    uint4* dst = (uint4*)eb;
    #pragma unroll
    for (int i = 0; i < 16; ++i) dst[i * 256 + t] = src[i * 256 + t];
  }
  __syncthreads();
  const int lane = t & 63, w = t >> 6;
  const int l15 = lane & 15, q = lane >> 4;
  const int r0 = blockIdx.x * 16;
  s8 rf = {0, 0, 0, 0, 0, 0, 0, 0};
  if (q < 2) rf = *(const s8*)&eb[(r0 + l15) * D_ + q * 8];
  const int c0 = w * 512;
  f4 acc[32];
  #pragma unroll
  for (int tl = 0; tl < 32; ++tl) {
    s8 cf = {0, 0, 0, 0, 0, 0, 0, 0};
    if (q < 2) cf = *(const s8*)&eb[(c0 + tl * 16 + l15) * D_ + q * 8];
    acc[tl] = __builtin_amdgcn_mfma_f32_16x16x32_bf16(cf, rf, (f4)0.0f, 0, 0, 0);
  }
  float m = acc[0][0];
  #pragma unroll
  for (int tl = 0; tl < 32; ++tl) {
    #pragma unroll
    for (int rg = 0; rg < 4; ++rg) m = fmaxf(m, acc[tl][rg]);
  }
  m = fmaxf(m, __shfl_xor(m, 16, 64));
  m = fmaxf(m, __shfl_xor(m, 32, 64));
  if (lane < 16) red[w][l15] = m;
  __syncthreads();
  const float gm = fmaxf(fmaxf(red[0][l15], red[1][l15]), fmaxf(red[2][l15], red[3][l15]));
  __syncthreads();
  float ps = 0.f;
  #pragma unroll
  for (int tl = 0; tl < 32; ++tl) {
    #pragma unroll
    for (int rg = 0; rg < 4; ++rg) {
      float v = __expf(acc[tl][rg] - gm);
      acc[tl][rg] = v;
      ps += v;
    }
  }
  ps += __shfl_xor(ps, 16, 64);
  ps += __shfl_xor(ps, 32, 64);
  if (lane < 16) red[w][l15] = ps;
  __syncthreads();
  const float inv = 1.0f / (red[0][l15] + red[1][l15] + red[2][l15] + red[3][l15]);
  ushort* Ar = (ushort*)A + (size_t)blockIdx.z * ((size_t)N_ * N_) +
               (size_t)(r0 + l15) * N_ + c0 + q * 4;
  #pragma unroll
  for (int tl = 0; tl < 32; ++tl) {
    uint2 pk;
    pk.x = packbf(acc[tl][0] * inv, acc[tl][1] * inv);
    pk.y = packbf(acc[tl][2] * inv, acc[tl][3] * inv);
    *(uint2*)&Ar[tl * 16] = pk;
  }
}

// ---------------------------------------------------------------- X^T[j=b*C+c][m] bf16 via LDS transpose
template <int MODE>  // 0: xs=[x,state]   1: cand=[x, z*state]
__global__ __launch_bounds__(256)
void k_buildX(const float* __restrict__ x, const float* __restrict__ state,
              const __hip_bfloat16* __restrict__ zbuf, __hip_bfloat16* __restrict__ XT) {
  constexpr int LDM = 72;
  __shared__ __align__(16) ushort T[C_ * LDM];
  const int t = threadIdx.x;
  const int m0 = blockIdx.x * 64, b = blockIdx.y;
  const int m = t >> 2, hq = t & 3;
  {
    const float* sp = state + ((size_t)b * N_ + m0 + m) * H_ + hq * 16;
    float sv[16];
    #pragma unroll
    for (int i = 0; i < 16; i += 4) {
      float4 v = *(const float4*)(sp + i);
      sv[i] = v.x; sv[i + 1] = v.y; sv[i + 2] = v.z; sv[i + 3] = v.w;
    }
    if (MODE) {
      const ushort* zp = (const ushort*)zbuf + ((size_t)b * N_ + m0 + m) * H_ + hq * 16;
      uint4 z0 = *(const uint4*)&zp[0], z1 = *(const uint4*)&zp[8];
      uint zw[8] = {z0.x, z0.y, z0.z, z0.w, z1.x, z1.y, z1.z, z1.w};
      #pragma unroll
      for (int i = 0; i < 8; ++i) {
        sv[2 * i]     *= bf2f((ushort)(zw[i] & 0xffffu));
        sv[2 * i + 1] *= bf2f((ushort)(zw[i] >> 16));
      }
    }
    #pragma unroll
    for (int i = 0; i < 16; ++i) T[(DIN + hq * 16 + i) * LDM + m] = f2bf(sv[i]);
    if (t < 64) {
      const float2 xv = *(const float2*)&x[((size_t)b * N_ + m0 + t) * DIN];
      T[0 * LDM + t] = f2bf(xv.x);
      T[1 * LDM + t] = f2bf(xv.y);
    }
  }
  __syncthreads();
  {
    int r = t >> 2, ch = t & 3;
    ushort* dst = (ushort*)XT + (size_t)(b * C_ + r) * N_ + m0 + ch * 16;
    *(uint4*)&dst[0] = *(uint4*)&T[r * LDM + ch * 16];
    *(uint4*)&dst[8] = *(uint4*)&T[r * LDM + ch * 16 + 8];
    if (t < 8) {
      r = 64 + (t >> 2);
      ushort* dst2 = (ushort*)XT + (size_t)(b * C_ + r) * N_ + m0 + ch * 16;
      *(uint4*)&dst2[0] = *(uint4*)&T[r * LDM + ch * 16];
      *(uint4*)&dst2[8] = *(uint4*)&T[r * LDM + ch * 16 + 8];
    }
  }
}

// ---------------------------------------------------------------- Y[r,j] = sum_m A[r,m] XT[j,m]
// R12-exact (measured best): SINGLE barrier per K-tile; 3-buffer distance-2
// prefetch, counted vmcnt(4); T1 XCD swizzle; T2 both-sides swizzle; T5 setprio.
__global__ __launch_bounds__(256)
void k_gemm(const __hip_bfloat16* __restrict__ Abase, size_t astride,
            const __hip_bfloat16* __restrict__ XT,
            __hip_bfloat16* __restrict__ Ybase, size_t ystride) {
  __shared__ __align__(16) ushort At[3][128 * 32];
  __shared__ __align__(16) ushort Xt[3][128 * 32];
  const int t = threadIdx.x;
  const int nwg = gridDim.x * gridDim.y * gridDim.z;   // 1056 or 528, both %8==0
  const int orig = blockIdx.x + gridDim.x * (blockIdx.y + gridDim.y * blockIdx.z);
  const int chunk = nwg >> 3;
  const int swz = (orig & 7) * chunk + (orig >> 3);
  const int bx = swz % gridDim.x;
  const int rest = swz / gridDim.x;
  const int by = rest % gridDim.y;
  const int bz = rest / gridDim.y;
  const int j0 = bx * 128, r0 = by * 128;
  const ushort* Ag = (const ushort*)Abase + (size_t)bz * astride;
  ushort* Y = (ushort*)Ybase + (size_t)bz * ystride;
  const int lane = t & 63, w = t >> 6;
  const int rowa = w * 32 + (lane >> 2);
  const int kc = (((lane & 3) ^ ((lane >> 3) & 3)) * 8);
  const ushort* pA0 = Ag + (size_t)(r0 + rowa) * N_ + kc;
  const ushort* pA1 = pA0 + 16 * N_;
  const ushort* pX0 = (const ushort*)XT + (size_t)(j0 + rowa) * N_ + kc;
  const ushort* pX1 = pX0 + 16 * N_;
  const int l15 = t & 15, q = (t >> 4) & 3;
  const int qs = (q ^ ((l15 >> 1) & 3)) * 8;
  const int wr = (w >> 1) * 64, wc = (w & 1) * 64;
  f4 acc[4][4];
  #pragma unroll
  for (int i = 0; i < 4; ++i)
    #pragma unroll
    for (int jj = 0; jj < 4; ++jj) acc[i][jj] = (f4)0.0f;
  #pragma unroll
  for (int p = 0; p < 2; ++p) {
    GLD16(pA0, &At[p][(w * 32) * 32]);
    GLD16(pA1, &At[p][(w * 32 + 16) * 32]);
    GLD16(pX0, &Xt[p][(w * 32) * 32]);
    GLD16(pX1, &Xt[p][(w * 32 + 16) * 32]);
    pA0 += 32; pA1 += 32; pX0 += 32; pX1 += 32;
  }
  int cur = 0, nx = 2;
  for (int k0 = 0; k0 < N_; k0 += 32) {
    if (k0 + 32 < N_) asm volatile("s_waitcnt vmcnt(4)" ::: "memory");
    else              asm volatile("s_waitcnt vmcnt(0)" ::: "memory");
    __builtin_amdgcn_s_barrier();           // tile-i data visible; tile-(i-1) reads done
    __builtin_amdgcn_sched_barrier(0);
    if (k0 + 64 < N_) {
      GLD16(pA0, &At[nx][(w * 32) * 32]);
      GLD16(pA1, &At[nx][(w * 32 + 16) * 32]);
      GLD16(pX0, &Xt[nx][(w * 32) * 32]);
      GLD16(pX1, &Xt[nx][(w * 32 + 16) * 32]);
      pA0 += 32; pA1 += 32; pX0 += 32; pX1 += 32;
    }
    s8 af[4], bfr[4];
    #pragma unroll
    for (int mi = 0; mi < 4; ++mi)
      af[mi] = *(const s8*)&At[cur][(wr + mi * 16 + l15) * 32 + qs];
    #pragma unroll
    for (int ni = 0; ni < 4; ++ni)
      bfr[ni] = *(const s8*)&Xt[cur][(wc + ni * 16 + l15) * 32 + qs];
    __builtin_amdgcn_s_setprio(1);
    #pragma unroll
    for (int mi = 0; mi < 4; ++mi)
      #pragma unroll
      for (int ni = 0; ni < 4; ++ni)
        acc[mi][ni] = __builtin_amdgcn_mfma_f32_16x16x32_bf16(af[mi], bfr[ni], acc[mi][ni], 0, 0, 0);
    __builtin_amdgcn_s_setprio(0);
    cur = cur == 2 ? 0 : cur + 1;
    nx = nx == 2 ? 0 : nx + 1;
  }
  // C/D: col = lane&15, row = quad*4 + reg  [verified m89/m91]
  #pragma unroll
  for (int mi = 0; mi < 4; ++mi) {
    int rr = r0 + wr + mi * 16 + q * 4;
    #pragma unroll
    for (int ni = 0; ni < 4; ++ni) {
      int cc = j0 + wc + ni * 16 + l15;
      #pragma unroll
      for (int rg = 0; rg < 4; ++rg)
        Y[(size_t)(rr + rg) * CB + cc] = f2bf(acc[mi][ni][rg]);
    }
  }
}

// ---------------------------------------------------------------- Wpb[j][16] bf16 = Wp[d][ki][o] transposed; j = o*KIP+ki, zero rows ki>=132
// Two (Wp, dst) pairs per dispatch (blockIdx.y selects) to merge z+r launches.
__global__ void k_wcvt(const float* __restrict__ Wp0, ushort* __restrict__ Wpb0,
                       const float* __restrict__ Wp1, ushort* __restrict__ Wpb1) {
  const float* Wp = blockIdx.y ? Wp1 : Wp0;
  ushort* Wpb = blockIdx.y ? Wpb1 : Wpb0;
  int j = blockIdx.x * 256 + threadIdx.x;   // 40 blocks x 256 = 10240
  if (j >= JW) return;
  int o = j / KIP, ki = j - o * KIP;
  ushort row[16];
  #pragma unroll
  for (int d = 0; d < 16; ++d) row[d] = 0;
  if (ki < KI) {
    #pragma unroll
    for (int d = 0; d < 16; ++d) row[d] = f2bf(Wp[((size_t)d * KI + ki) * 64 + o]);
  }
  *(uint4*)&Wpb[(size_t)j * 16] = *(uint4*)&row[0];
  *(uint4*)&Wpb[(size_t)j * 16 + 8] = *(uint4*)&row[8];
}

// ---------------------------------------------------------------- Wmf[n][ks][o][32] bf16 = sum_d e[n,d] Wpb[j][d] via MFMA
// FRAGMENT-ORDER output layout: index = n*JW + ks*2048 + o*32 + (ki&31),
// ks = ki/32 — so einsum's per-wave B-frag read is one contiguous 1KB block.
// jt = o*10 + s (s=0..9): ki = s*16 + l15 -> ks = s>>1, ki&31 = (s&1)*16 + l15.
// A-frag: 16 e-rows (K=32, upper half zero; packed in-reg from fp32 e).
__global__ __launch_bounds__(256)
void k_wmat3(const float* __restrict__ eg, const ushort* __restrict__ Wpb, ushort* __restrict__ Wm) {
  const int t = threadIdx.x;
  const int lane = t & 63, w = t >> 6;
  const int l15 = lane & 15, q = lane >> 4;
  const int n0 = blockIdx.x * 16;
  s8 af = {0, 0, 0, 0, 0, 0, 0, 0};
  if (q < 2) {
    const float* ep = eg + (size_t)(n0 + l15) * D_ + q * 8;
    float4 v0 = *(const float4*)ep, v1 = *(const float4*)(ep + 4);
    ushort pk[8] = {f2bf(v0.x), f2bf(v0.y), f2bf(v0.z), f2bf(v0.w),
                    f2bf(v1.x), f2bf(v1.y), f2bf(v1.z), f2bf(v1.w)};
    af = *(const s8*)pk;
  }
  const int o0 = blockIdx.y * 8 + w * 2;   // 64 o's / 8 y-blocks / 4 waves * 2
  ushort* wbase = Wm + (size_t)(n0 + q * 4) * JW;
  #pragma unroll
  for (int oo = 0; oo < 2; ++oo) {
    const int o = o0 + oo;
    #pragma unroll
    for (int s = 0; s < 10; ++s) {
      const int jt = o * 10 + s;
      s8 bfr = {0, 0, 0, 0, 0, 0, 0, 0};
      if (q < 2) bfr = *(const s8*)&Wpb[(size_t)(jt * 16 + l15) * 16 + q * 8];
      f4 acc = __builtin_amdgcn_mfma_f32_16x16x32_bf16(af, bfr, (f4)0.0f, 0, 0, 0);
      const size_t idx = (size_t)((s >> 1) * 2048 + o * 32 + (s & 1) * 16 + l15);
      #pragma unroll
      for (int rg = 0; rg < 4; ++rg)
        wbase[(size_t)rg * JW + idx] = f2bf(acc[rg]);
    }
  }
}

// ---------------------------------------------------------------- per-node einsum via MFMA; B-frags COALESCED from fragment-order Wm
template <int MODE>  // 0: sigmoid -> bf16 gate buf ; 1: tanh + GRU combine -> fp32 d_out
__global__ __launch_bounds__(256)
void k_einsum(const float* __restrict__ e, const ushort* __restrict__ Wm, const float* __restrict__ bp,
              const __hip_bfloat16* __restrict__ Y,
              const float* __restrict__ x, const float* __restrict__ state,
              const __hip_bfloat16* __restrict__ zbuf, const __hip_bfloat16* __restrict__ rbuf,
              void* __restrict__ outp) {
  constexpr int LDK = 168;
  constexpr int LDR = 72;
  __shared__ __align__(16) ushort xg[64 * LDK];
  __shared__ __align__(16) ushort res[64 * LDR];
  __shared__ float bl[64];
  const int n = blockIdx.x, t = threadIdx.x;
  if (t < 64) {
    float s = 0.f;
    const float* ep = e + (size_t)n * D_;
    #pragma unroll
    for (int d = 0; d < D_; ++d) s += ep[d] * bp[d * 64 + t];   // e: L1 broadcast
    bl[t] = s;
  }
  {
    const int b = t >> 2, j = t & 3;
    const size_t bn = (size_t)b * N_ + n;
    float sv[16];
    const float* sp = state + bn * 64 + j * 16;
    #pragma unroll
    for (int i = 0; i < 16; i += 4) {
      float4 v = *(const float4*)(sp + i);
      sv[i] = v.x; sv[i + 1] = v.y; sv[i + 2] = v.z; sv[i + 3] = v.w;
    }
    if (MODE) {
      const ushort* zp = (const ushort*)zbuf + bn * 64 + j * 16;
      uint4 z0 = *(const uint4*)&zp[0], z1 = *(const uint4*)&zp[8];
      uint zw[8] = {z0.x, z0.y, z0.z, z0.w, z1.x, z1.y, z1.z, z1.w};
      #pragma unroll
      for (int i = 0; i < 8; ++i) {
        sv[2 * i]     *= bf2f((ushort)(zw[i] & 0xffffu));
        sv[2 * i + 1] *= bf2f((ushort)(zw[i] >> 16));
      }
    }
    ushort* xr = &xg[b * LDK + 2 + j * 16];
    #pragma unroll
    for (int i = 0; i < 16; i += 2) {
      uint pk = packbf(sv[i], sv[i + 1]);
      *(uint*)&xr[i] = pk;
    }
    const ushort* yp = (const ushort*)Y + (size_t)n * CB + b * C_ + j * 16;
    uint* xy = (uint*)&xg[b * LDK + 66 + j * 16];
    #pragma unroll
    for (int i = 0; i < 8; ++i) xy[i] = *(const uint*)&yp[2 * i];
    if (j == 0) *(uint*)&xg[b * LDK + 130] = *(const uint*)&yp[64];
    if (t < 64) {
      const float* xp = x + ((size_t)t * N_ + n) * DIN;
      uint pk = packbf(xp[0], xp[1]);
      *(uint*)&xg[t * LDK] = pk;
    }
    ushort* pg = &xg[b * LDK + 132 + j * 7];
    #pragma unroll
    for (int i = 0; i < 7; ++i) pg[i] = 0;
  }
  __syncthreads();
  const int l15 = t & 15, q = (t >> 4) & 3, w = t >> 6;
  const int wm = (w >> 1) * 32, wn = (w & 1) * 32;
  const ushort* Wn = Wm + (size_t)n * JW;
  f4 acc[2][2];
  acc[0][0] = acc[0][1] = acc[1][0] = acc[1][1] = (f4)0.0f;
  #pragma unroll
  for (int ks = 0; ks < 5; ++ks) {
    s8 af[2], bfr[2];
    #pragma unroll
    for (int mi = 0; mi < 2; ++mi) af[mi] = *(const s8*)&xg[(wm + mi * 16 + l15) * LDK + ks * 32 + q * 8];
    #pragma unroll
    for (int ni = 0; ni < 2; ++ni)
      bfr[ni] = *(const s8*)(Wn + ks * 2048 + (wn + ni * 16 + l15) * 32 + q * 8);  // coalesced 1KB/wave
    #pragma unroll
    for (int mi = 0; mi < 2; ++mi)
      #pragma unroll
      for (int ni = 0; ni < 2; ++ni)
        acc[mi][ni] = __builtin_amdgcn_mfma_f32_16x16x32_bf16(af[mi], bfr[ni], acc[mi][ni], 0, 0, 0);
  }
  {
    float bl0 = bl[wn + l15], bl1 = bl[wn + 16 + l15];
    #pragma unroll
    for (int mi = 0; mi < 2; ++mi)
      #pragma unroll
      for (int ni = 0; ni < 2; ++ni) {
        float bb = ni ? bl1 : bl0;
        #pragma unroll
        for (int rg = 0; rg < 4; ++rg) {
          float v = acc[mi][ni][rg] + bb;
          float a;
          if (MODE == 0) a = 1.0f / (1.0f + __expf(-v));
          else           a = 1.0f - 2.0f / (__expf(2.0f * v) + 1.0f);
          res[(wm + mi * 16 + q * 4 + rg) * LDR + (wn + ni * 16 + l15)] = f2bf(a);
        }
      }
  }
  __syncthreads();
  {
    const int b = t >> 2, j = t & 3;
    const size_t gb = ((size_t)b * N_ + n) * 64 + j * 16;
    const ushort* rr = &res[b * LDR + j * 16];
    if (MODE == 0) {
      uint4 v0 = *(const uint4*)&rr[0];
      uint4 v1 = *(const uint4*)&rr[8];
      *(uint4*)((ushort*)outp + gb) = v0;
      *(uint4*)((ushort*)outp + gb + 8) = v1;
    } else {
      float* ob = (float*)outp;
      const float* stp = state + gb;
      const ushort* rp = (const ushort*)rbuf + gb;
      uint4 r0 = *(const uint4*)&rp[0], r1 = *(const uint4*)&rp[8];
      uint rw[8] = {r0.x, r0.y, r0.z, r0.w, r1.x, r1.y, r1.z, r1.w};
      #pragma unroll
      for (int i = 0; i < 16; i += 4) {
        float4 st = *(const float4*)(stp + i);
        float4 ov;
        float rv0 = bf2f((ushort)(rw[i / 2] & 0xffffu));
        float rv1 = bf2f((ushort)(rw[i / 2] >> 16));
        float rv2 = bf2f((ushort)(rw[i / 2 + 1] & 0xffffu));
        float rv3 = bf2f((ushort)(rw[i / 2 + 1] >> 16));
        ov.x = rv0 * st.x + (1.0f - rv0) * bf2f(rr[i]);
        ov.y = rv1 * st.y + (1.0f - rv1) * bf2f(rr[i + 1]);
        ov.z = rv2 * st.z + (1.0f - rv2) * bf2f(rr[i + 2]);
        ov.w = rv3 * st.w + (1.0f - rv3) * bf2f(rr[i + 3]);
        *(float4*)(ob + gb + i) = ov;
      }
    }
  }
}

// ----------------------------------------------------------------
extern "C" void kernel_launch(void* const* d_in, const int* in_sizes, int n_in,
                              void* d_out, int out_size, void* d_ws, size_t ws_size,
                              hipStream_t stream) {
  const float* x     = (const float*)d_in[0];
  const float* state = (const float*)d_in[1];
  const float* node  = (const float*)d_in[2];
  const float* timee = (const float*)d_in[3];
  const float* W_z = (const float*)d_in[4];
  const float* b_z = (const float*)d_in[5];
  const float* g_z = (const float*)d_in[6];
  const float* be_z = (const float*)d_in[7];
  const float* W_r = (const float*)d_in[8];
  const float* b_r = (const float*)d_in[9];
  const float* g_r = (const float*)d_in[10];
  const float* be_r = (const float*)d_in[11];
  const float* W_u = (const float*)d_in[12];
  const float* b_u = (const float*)d_in[13];
  const float* g_u = (const float*)d_in[14];
  const float* be_u = (const float*)d_in[15];

  constexpr size_t NN = (size_t)N_ * N_;
  constexpr size_t ND = (size_t)N_ * D_;
  char* ws = (char*)d_ws;
  float*           e  = (float*)(ws);                        //       0 :    393,216
  __hip_bfloat16*  A  = (__hip_bfloat16*)(ws + 393216);      //  25,165,824
  __hip_bfloat16*  XT = (__hip_bfloat16*)(ws + 25559040);    //  17,301,504
  __hip_bfloat16*  Y  = (__hip_bfloat16*)(ws + 42860544);    //  17,301,504
  __hip_bfloat16*  zb = (__hip_bfloat16*)(ws + 60162048);    //  16,777,216
  __hip_bfloat16*  rb = (__hip_bfloat16*)(ws + 76939264);    //  16,777,216
  ushort*          ebf = (ushort*)(ws + 93716480);           //  196,608 (dead before Wm written)
  ushort*          Wm = (ushort*)(ws + 93716480);            //  41,943,040 (ends 135,659,520)
  __hip_bfloat16*  Yr = (__hip_bfloat16*)(ws + 135659520);   //  17,301,504 (big-ws only)
  const size_t YRD = ((size_t)135659520 - 42860544) / 2;
  const bool big = ws_size >= (size_t)152961024;
  // Wpb scratch (327,680 B) in provably-dead windows:
  //  z: zb base (einsum z writes zb AFTER wmat3 z consumed Wpb_z)
  //  r: rb base (einsum r writes rb AFTER wmat3 r consumed Wpb_r)
  //  u: A_z panel base (dead after the z(+r) GEMM; wcvt u runs after einsum r)
  ushort* Wpb_z = (ushort*)(ws + 60162048);
  ushort* Wpb_r = (ushort*)(ws + 76939264);
  ushort* Wpb_u = (ushort*)(ws + 393216);

  float* out = (float*)d_out;

  k_e<<<8, 256, 0, stream>>>(node, timee, g_z, be_z, g_r, be_r, g_u, be_u, e, ebf);
  k_attn<<<dim3(N_ / 16, 1, 3), 256, 0, stream>>>(ebf, A);
  k_buildX<0><<<dim3(32, 64), 256, 0, stream>>>(x, state, nullptr, XT);

  dim3 ggrid1(CB / 128, N_ / 128, 1);   // 528 blocks (%8==0)
  dim3 ggrid2(CB / 128, N_ / 128, 2);   // fused z+r: 1056 blocks (%8==0)
  dim3 wgrid3(N_ / 16, 8);              // k_wmat3: 1024 blocks

  if (big) {
    k_wcvt<<<dim3(40, 2), 256, 0, stream>>>(W_z, Wpb_z, W_r, Wpb_r);
    k_wmat3<<<wgrid3, 256, 0, stream>>>(e + 0 * ND, Wpb_z, Wm);
    k_gemm<<<ggrid2, 256, 0, stream>>>(A, NN, XT, Y, YRD);                       // z->Y, r->Yr
    k_einsum<0><<<N_, 256, 0, stream>>>(e + 0 * ND, Wm, b_z, Y, x, state, nullptr, nullptr, (void*)zb);
    k_wmat3<<<wgrid3, 256, 0, stream>>>(e + 1 * ND, Wpb_r, Wm);
    k_einsum<0><<<N_, 256, 0, stream>>>(e + 1 * ND, Wm, b_r, Yr, x, state, nullptr, nullptr, (void*)rb);
  } else {
    k_wcvt<<<dim3(40, 2), 256, 0, stream>>>(W_z, Wpb_z, W_r, Wpb_r);
    k_wmat3<<<wgrid3, 256, 0, stream>>>(e + 0 * ND, Wpb_z, Wm);
    k_gemm<<<ggrid1, 256, 0, stream>>>(A, 0, XT, Y, 0);
    k_einsum<0><<<N_, 256, 0, stream>>>(e + 0 * ND, Wm, b_z, Y, x, state, nullptr, nullptr, (void*)zb);
    k_wmat3<<<wgrid3, 256, 0, stream>>>(e + 1 * ND, Wpb_r, Wm);
    k_gemm<<<ggrid1, 256, 0, stream>>>(A + NN, 0, XT, Y, 0);
    k_einsum<0><<<N_, 256, 0, stream>>>(e + 1 * ND, Wm, b_r, Y, x, state, nullptr, nullptr, (void*)rb);
  }
  // gate u: cand = [x, z*state]
  k_buildX<1><<<dim3(32, 64), 256, 0, stream>>>(x, state, zb, XT);
  k_wcvt<<<dim3(40, 1), 256, 0, stream>>>(W_u, Wpb_u, W_u, Wpb_u);   // A_z panel dead by now
  k_wmat3<<<wgrid3, 256, 0, stream>>>(e + 2 * ND, Wpb_u, Wm);
  k_gemm<<<ggrid1, 256, 0, stream>>>(A + 2 * NN, 0, XT, Y, 0);
  k_einsum<1><<<N_, 256, 0, stream>>>(e + 2 * ND, Wm, b_u, Y, x, state, zb, rb, (void*)out);
}

// Round 10
// 412.973 us; speedup vs baseline: 1.4942x; 1.0235x over previous
//
#include <hip/hip_runtime.h>
#include <hip/hip_bf16.h>
#include <math.h>

// GRUCell with adaptive-graph GCN on MI355X (gfx950).
// B=64, N=2048, Din=2, H=64, D=16, C=66, O=64.
// R18: dispatch-count reduction 14 -> 10 via dependency-checked merges:
//      fuse1 = k_e + wcvt(z) + wcvt(r)            [88 blocks]
//      fuse3 = buildX<0> + wmat3(z)               [3072 blocks]
//      fuse6 = buildX<1> + wmat3(r) + wcvt(u)     [3112 blocks]
//      (each boundary on a 256-CU chip costs tail-drain + ramp; kernels herein
//      are short, so boundaries are a real fraction of the 258us non-gemm time)
//      + einsum: hoist ks=0..2 B-frags to regs before xg build (T14; +24 VGPR,
//      stays at 5 blocks/CU). k_gemm / k_attn / k_einsum cores unchanged.
//      8-phase gemm port evaluated and deliberately skipped: blind
//      reconstruction of the half-tile staging discipline is race-prone
//      (m152) and tail quantization caps the upside here.

typedef __attribute__((ext_vector_type(4))) float f4;
typedef __attribute__((ext_vector_type(8))) short s8;  // 8 bf16 in 4 VGPRs (MFMA A/B frag)

#define B_   64
#define N_   2048
#define DIN  2
#define H_   64
#define D_   16
#define C_   66    // DIN + H
#define KI   132   // 2*C
#define KIP  160   // KI padded for K-loop (multiple of 32)
#define CB   4224  // B_*C_
#define JW   10240 // Wm row length per node (5 ks-planes x 64 o x 32)

#define GLD16(gp, lp) __builtin_amdgcn_global_load_lds((const __attribute__((address_space(1))) void*)(gp), (__attribute__((address_space(3))) void*)(lp), 16, 0, 0)

static __device__ __forceinline__ ushort f2bf(float v) {
  __hip_bfloat16 h = __float2bfloat16(v);
  return *(ushort*)&h;
}
static __device__ __forceinline__ float bf2f(ushort u) {
  __hip_bfloat16 h = *(__hip_bfloat16*)&u;
  return __bfloat162float(h);
}
static __device__ __forceinline__ uint packbf(float a, float b) {
  return ((uint)f2bf(b) << 16) | f2bf(a);
}

// ---------------------------------------------------------------- device bodies

// e = LN(node+time)*gamma+beta (fp32 + bf16 copies); one "block" = 256 nodes
static __device__ void dev_e(const float* __restrict__ node, const float* __restrict__ timee,
                             const float* __restrict__ g0, const float* __restrict__ b0,
                             const float* __restrict__ g1, const float* __restrict__ b1,
                             const float* __restrict__ g2, const float* __restrict__ b2,
                             float* __restrict__ e, ushort* __restrict__ ebf,
                             int bid, int t) {
  int n = bid * 256 + t;
  if (n >= N_) return;
  float v[D_]; float m = 0.f;
  #pragma unroll
  for (int d = 0; d < D_; ++d) { v[d] = node[n * D_ + d] + timee[d]; m += v[d]; }
  m *= (1.0f / D_);
  float var = 0.f;
  #pragma unroll
  for (int d = 0; d < D_; ++d) { float tt = v[d] - m; var += tt * tt; }
  var *= (1.0f / D_);
  float r = rsqrtf(var + 1e-12f);
  float y[D_];
  #pragma unroll
  for (int d = 0; d < D_; ++d) y[d] = (v[d] - m) * r;
  const float* gs[3] = {g0, g1, g2};
  const float* bs[3] = {b0, b1, b2};
  #pragma unroll
  for (int g = 0; g < 3; ++g) {
    #pragma unroll
    for (int d = 0; d < D_; d += 2) {
      float o0 = y[d] * gs[g][d] + bs[g][d];
      float o1 = y[d + 1] * gs[g][d + 1] + bs[g][d + 1];
      e[g * N_ * D_ + n * D_ + d] = o0;
      e[g * N_ * D_ + n * D_ + d + 1] = o1;
      *(uint*)&ebf[g * N_ * D_ + n * D_ + d] = packbf(o0, o1);
    }
  }
}

// Wpb[j][16] bf16 = Wp[d][ki][o] transposed; j = o*KIP+ki, zero rows ki>=132
static __device__ void dev_wcvt(const float* __restrict__ Wp, ushort* __restrict__ Wpb,
                                int bid, int t) {
  int j = bid * 256 + t;   // 40 blocks x 256 = 10240
  if (j >= JW) return;
  int o = j / KIP, ki = j - o * KIP;
  ushort row[16];
  #pragma unroll
  for (int d = 0; d < 16; ++d) row[d] = 0;
  if (ki < KI) {
    #pragma unroll
    for (int d = 0; d < 16; ++d) row[d] = f2bf(Wp[((size_t)d * KI + ki) * 64 + o]);
  }
  *(uint4*)&Wpb[(size_t)j * 16] = *(uint4*)&row[0];
  *(uint4*)&Wpb[(size_t)j * 16 + 8] = *(uint4*)&row[8];
}

// X^T[j=b*C+c][m] bf16 via LDS transpose; shared T passed in
template <int MODE>  // 0: xs=[x,state]   1: cand=[x, z*state]
static __device__ void dev_buildX(const float* __restrict__ x, const float* __restrict__ state,
                                  const __hip_bfloat16* __restrict__ zbuf, __hip_bfloat16* __restrict__ XT,
                                  ushort* T, int bxm, int bxb, int t) {
  constexpr int LDM = 72;
  const int m0 = bxm * 64, b = bxb;
  const int m = t >> 2, hq = t & 3;
  {
    const float* sp = state + ((size_t)b * N_ + m0 + m) * H_ + hq * 16;
    float sv[16];
    #pragma unroll
    for (int i = 0; i < 16; i += 4) {
      float4 v = *(const float4*)(sp + i);
      sv[i] = v.x; sv[i + 1] = v.y; sv[i + 2] = v.z; sv[i + 3] = v.w;
    }
    if (MODE) {
      const ushort* zp = (const ushort*)zbuf + ((size_t)b * N_ + m0 + m) * H_ + hq * 16;
      uint4 z0 = *(const uint4*)&zp[0], z1 = *(const uint4*)&zp[8];
      uint zw[8] = {z0.x, z0.y, z0.z, z0.w, z1.x, z1.y, z1.z, z1.w};
      #pragma unroll
      for (int i = 0; i < 8; ++i) {
        sv[2 * i]     *= bf2f((ushort)(zw[i] & 0xffffu));
        sv[2 * i + 1] *= bf2f((ushort)(zw[i] >> 16));
      }
    }
    #pragma unroll
    for (int i = 0; i < 16; ++i) T[(DIN + hq * 16 + i) * LDM + m] = f2bf(sv[i]);
    if (t < 64) {
      const float2 xv = *(const float2*)&x[((size_t)b * N_ + m0 + t) * DIN];
      T[0 * LDM + t] = f2bf(xv.x);
      T[1 * LDM + t] = f2bf(xv.y);
    }
  }
  __syncthreads();
  {
    int r = t >> 2, ch = t & 3;
    ushort* dst = (ushort*)XT + (size_t)(b * C_ + r) * N_ + m0 + ch * 16;
    *(uint4*)&dst[0] = *(uint4*)&T[r * LDM + ch * 16];
    *(uint4*)&dst[8] = *(uint4*)&T[r * LDM + ch * 16 + 8];
    if (t < 8) {
      r = 64 + (t >> 2);
      ushort* dst2 = (ushort*)XT + (size_t)(b * C_ + r) * N_ + m0 + ch * 16;
      *(uint4*)&dst2[0] = *(uint4*)&T[r * LDM + ch * 16];
      *(uint4*)&dst2[8] = *(uint4*)&T[r * LDM + ch * 16 + 8];
    }
  }
}

// Wmf[n][ks][o][32] bf16 = sum_d e[n,d] Wpb[j][d] via MFMA (fragment-order out)
static __device__ void dev_wmat3(const float* __restrict__ eg, const ushort* __restrict__ Wpb,
                                 ushort* __restrict__ Wm, int bnx, int bny, int t) {
  const int lane = t & 63, w = t >> 6;
  const int l15 = lane & 15, q = lane >> 4;
  const int n0 = bnx * 16;
  s8 af = {0, 0, 0, 0, 0, 0, 0, 0};
  if (q < 2) {
    const float* ep = eg + (size_t)(n0 + l15) * D_ + q * 8;
    float4 v0 = *(const float4*)ep, v1 = *(const float4*)(ep + 4);
    ushort pk[8] = {f2bf(v0.x), f2bf(v0.y), f2bf(v0.z), f2bf(v0.w),
                    f2bf(v1.x), f2bf(v1.y), f2bf(v1.z), f2bf(v1.w)};
    af = *(const s8*)pk;
  }
  const int o0 = bny * 8 + w * 2;
  ushort* wbase = Wm + (size_t)(n0 + q * 4) * JW;
  #pragma unroll
  for (int oo = 0; oo < 2; ++oo) {
    const int o = o0 + oo;
    #pragma unroll
    for (int s = 0; s < 10; ++s) {
      const int jt = o * 10 + s;
      s8 bfr = {0, 0, 0, 0, 0, 0, 0, 0};
      if (q < 2) bfr = *(const s8*)&Wpb[(size_t)(jt * 16 + l15) * 16 + q * 8];
      f4 acc = __builtin_amdgcn_mfma_f32_16x16x32_bf16(af, bfr, (f4)0.0f, 0, 0, 0);
      const size_t idx = (size_t)((s >> 1) * 2048 + o * 32 + (s & 1) * 16 + l15);
      #pragma unroll
      for (int rg = 0; rg < 4; ++rg)
        wbase[(size_t)rg * JW + idx] = f2bf(acc[rg]);
    }
  }
}

// ---------------------------------------------------------------- fused dispatchers
__global__ __launch_bounds__(256)
void k_fuse1(const float* __restrict__ node, const float* __restrict__ timee,
             const float* __restrict__ g0, const float* __restrict__ b0,
             const float* __restrict__ g1, const float* __restrict__ b1,
             const float* __restrict__ g2, const float* __restrict__ b2,
             float* __restrict__ e, ushort* __restrict__ ebf,
             const float* __restrict__ Wpz, ushort* __restrict__ Wpbz,
             const float* __restrict__ Wpr, ushort* __restrict__ Wpbr) {
  const int bid = blockIdx.x, t = threadIdx.x;
  if (bid < 8)       dev_e(node, timee, g0, b0, g1, b1, g2, b2, e, ebf, bid, t);
  else if (bid < 48) dev_wcvt(Wpz, Wpbz, bid - 8, t);
  else               dev_wcvt(Wpr, Wpbr, bid - 48, t);
}

__global__ __launch_bounds__(256)
void k_fuse3(const float* __restrict__ x, const float* __restrict__ state,
             __hip_bfloat16* __restrict__ XT,
             const float* __restrict__ eg, const ushort* __restrict__ Wpb,
             ushort* __restrict__ Wm) {
  __shared__ __align__(16) ushort T[C_ * 72];
  const int bid = blockIdx.x, t = threadIdx.x;
  if (bid < 2048) dev_buildX<0>(x, state, nullptr, XT, T, bid & 31, bid >> 5, t);
  else            dev_wmat3(eg, Wpb, Wm, (bid - 2048) & 127, (bid - 2048) >> 7, t);
}

__global__ __launch_bounds__(256)
void k_fuse6(const float* __restrict__ x, const float* __restrict__ state,
             const __hip_bfloat16* __restrict__ zbuf, __hip_bfloat16* __restrict__ XT,
             const float* __restrict__ eg, const ushort* __restrict__ Wpb,
             ushort* __restrict__ Wm,
             const float* __restrict__ Wpu, ushort* __restrict__ Wpbu) {
  __shared__ __align__(16) ushort T[C_ * 72];
  const int bid = blockIdx.x, t = threadIdx.x;
  if (bid < 2048)      dev_buildX<1>(x, state, zbuf, XT, T, bid & 31, bid >> 5, t);
  else if (bid < 3072) dev_wmat3(eg, Wpb, Wm, (bid - 2048) & 127, (bid - 2048) >> 7, t);
  else                 dev_wcvt(Wpu, Wpbu, bid - 3072, t);
}

// ---------------------------------------------------------------- standalone: buildX (small-ws path), wcvt, wmat3
template <int MODE>
__global__ __launch_bounds__(256)
void k_buildX(const float* __restrict__ x, const float* __restrict__ state,
              const __hip_bfloat16* __restrict__ zbuf, __hip_bfloat16* __restrict__ XT) {
  __shared__ __align__(16) ushort T[C_ * 72];
  dev_buildX<MODE>(x, state, zbuf, XT, T, blockIdx.x, blockIdx.y, threadIdx.x);
}

__global__ __launch_bounds__(256)
void k_wcvt1(const float* __restrict__ Wp, ushort* __restrict__ Wpb) {
  dev_wcvt(Wp, Wpb, blockIdx.x, threadIdx.x);
}

__global__ __launch_bounds__(256)
void k_wmat3(const float* __restrict__ eg, const ushort* __restrict__ Wpb, ushort* __restrict__ Wm) {
  dev_wmat3(eg, Wpb, Wm, blockIdx.x, blockIdx.y, threadIdx.x);
}

// ---------------------------------------------------------------- fused A_g = softmax(e_g e_g^T, axis=1), bf16
__global__ __launch_bounds__(256)
void k_attn(const ushort* __restrict__ ebf, __hip_bfloat16* __restrict__ A) {
  __shared__ __align__(16) ushort eb[N_ * D_];   // 64 KB
  __shared__ float red[4][16];
  const int t = threadIdx.x;
  const ushort* eg = ebf + (size_t)blockIdx.z * (N_ * D_);
  {
    const uint4* src = (const uint4*)eg;
    uint4* dst = (uint4*)eb;
    #pragma unroll
    for (int i = 0; i < 16; ++i) dst[i * 256 + t] = src[i * 256 + t];
  }
  __syncthreads();
  const int lane = t & 63, w = t >> 6;
  const int l15 = lane & 15, q = lane >> 4;
  const int r0 = blockIdx.x * 16;
  s8 rf = {0, 0, 0, 0, 0, 0, 0, 0};
  if (q < 2) rf = *(const s8*)&eb[(r0 + l15) * D_ + q * 8];
  const int c0 = w * 512;
  f4 acc[32];
  #pragma unroll
  for (int tl = 0; tl < 32; ++tl) {
    s8 cf = {0, 0, 0, 0, 0, 0, 0, 0};
    if (q < 2) cf = *(const s8*)&eb[(c0 + tl * 16 + l15) * D_ + q * 8];
    acc[tl] = __builtin_amdgcn_mfma_f32_16x16x32_bf16(cf, rf, (f4)0.0f, 0, 0, 0);
  }
  float m = acc[0][0];
  #pragma unroll
  for (int tl = 0; tl < 32; ++tl) {
    #pragma unroll
    for (int rg = 0; rg < 4; ++rg) m = fmaxf(m, acc[tl][rg]);
  }
  m = fmaxf(m, __shfl_xor(m, 16, 64));
  m = fmaxf(m, __shfl_xor(m, 32, 64));
  if (lane < 16) red[w][l15] = m;
  __syncthreads();
  const float gm = fmaxf(fmaxf(red[0][l15], red[1][l15]), fmaxf(red[2][l15], red[3][l15]));
  __syncthreads();
  float ps = 0.f;
  #pragma unroll
  for (int tl = 0; tl < 32; ++tl) {
    #pragma unroll
    for (int rg = 0; rg < 4; ++rg) {
      float v = __expf(acc[tl][rg] - gm);
      acc[tl][rg] = v;
      ps += v;
    }
  }
  ps += __shfl_xor(ps, 16, 64);
  ps += __shfl_xor(ps, 32, 64);
  if (lane < 16) red[w][l15] = ps;
  __syncthreads();
  const float inv = 1.0f / (red[0][l15] + red[1][l15] + red[2][l15] + red[3][l15]);
  ushort* Ar = (ushort*)A + (size_t)blockIdx.z * ((size_t)N_ * N_) +
               (size_t)(r0 + l15) * N_ + c0 + q * 4;
  #pragma unroll
  for (int tl = 0; tl < 32; ++tl) {
    uint2 pk;
    pk.x = packbf(acc[tl][0] * inv, acc[tl][1] * inv);
    pk.y = packbf(acc[tl][2] * inv, acc[tl][3] * inv);
    *(uint2*)&Ar[tl * 16] = pk;
  }
}

// ---------------------------------------------------------------- Y[r,j] = sum_m A[r,m] XT[j,m]
// R12-exact (measured best): SINGLE barrier per K-tile; 3-buffer distance-2
// prefetch, counted vmcnt(4); T1 XCD swizzle; T2 both-sides swizzle; T5 setprio.
__global__ __launch_bounds__(256)
void k_gemm(const __hip_bfloat16* __restrict__ Abase, size_t astride,
            const __hip_bfloat16* __restrict__ XT,
            __hip_bfloat16* __restrict__ Ybase, size_t ystride) {
  __shared__ __align__(16) ushort At[3][128 * 32];
  __shared__ __align__(16) ushort Xt[3][128 * 32];
  const int t = threadIdx.x;
  const int nwg = gridDim.x * gridDim.y * gridDim.z;   // 1056 or 528, both %8==0
  const int orig = blockIdx.x + gridDim.x * (blockIdx.y + gridDim.y * blockIdx.z);
  const int chunk = nwg >> 3;
  const int swz = (orig & 7) * chunk + (orig >> 3);
  const int bx = swz % gridDim.x;
  const int rest = swz / gridDim.x;
  const int by = rest % gridDim.y;
  const int bz = rest / gridDim.y;
  const int j0 = bx * 128, r0 = by * 128;
  const ushort* Ag = (const ushort*)Abase + (size_t)bz * astride;
  ushort* Y = (ushort*)Ybase + (size_t)bz * ystride;
  const int lane = t & 63, w = t >> 6;
  const int rowa = w * 32 + (lane >> 2);
  const int kc = (((lane & 3) ^ ((lane >> 3) & 3)) * 8);
  const ushort* pA0 = Ag + (size_t)(r0 + rowa) * N_ + kc;
  const ushort* pA1 = pA0 + 16 * N_;
  const ushort* pX0 = (const ushort*)XT + (size_t)(j0 + rowa) * N_ + kc;
  const ushort* pX1 = pX0 + 16 * N_;
  const int l15 = t & 15, q = (t >> 4) & 3;
  const int qs = (q ^ ((l15 >> 1) & 3)) * 8;
  const int wr = (w >> 1) * 64, wc = (w & 1) * 64;
  f4 acc[4][4];
  #pragma unroll
  for (int i = 0; i < 4; ++i)
    #pragma unroll
    for (int jj = 0; jj < 4; ++jj) acc[i][jj] = (f4)0.0f;
  #pragma unroll
  for (int p = 0; p < 2; ++p) {
    GLD16(pA0, &At[p][(w * 32) * 32]);
    GLD16(pA1, &At[p][(w * 32 + 16) * 32]);
    GLD16(pX0, &Xt[p][(w * 32) * 32]);
    GLD16(pX1, &Xt[p][(w * 32 + 16) * 32]);
    pA0 += 32; pA1 += 32; pX0 += 32; pX1 += 32;
  }
  int cur = 0, nx = 2;
  for (int k0 = 0; k0 < N_; k0 += 32) {
    if (k0 + 32 < N_) asm volatile("s_waitcnt vmcnt(4)" ::: "memory");
    else              asm volatile("s_waitcnt vmcnt(0)" ::: "memory");
    __builtin_amdgcn_s_barrier();           // tile-i data visible; tile-(i-1) reads done
    __builtin_amdgcn_sched_barrier(0);
    if (k0 + 64 < N_) {
      GLD16(pA0, &At[nx][(w * 32) * 32]);
      GLD16(pA1, &At[nx][(w * 32 + 16) * 32]);
      GLD16(pX0, &Xt[nx][(w * 32) * 32]);
      GLD16(pX1, &Xt[nx][(w * 32 + 16) * 32]);
      pA0 += 32; pA1 += 32; pX0 += 32; pX1 += 32;
    }
    s8 af[4], bfr[4];
    #pragma unroll
    for (int mi = 0; mi < 4; ++mi)
      af[mi] = *(const s8*)&At[cur][(wr + mi * 16 + l15) * 32 + qs];
    #pragma unroll
    for (int ni = 0; ni < 4; ++ni)
      bfr[ni] = *(const s8*)&Xt[cur][(wc + ni * 16 + l15) * 32 + qs];
    __builtin_amdgcn_s_setprio(1);
    #pragma unroll
    for (int mi = 0; mi < 4; ++mi)
      #pragma unroll
      for (int ni = 0; ni < 4; ++ni)
        acc[mi][ni] = __builtin_amdgcn_mfma_f32_16x16x32_bf16(af[mi], bfr[ni], acc[mi][ni], 0, 0, 0);
    __builtin_amdgcn_s_setprio(0);
    cur = cur == 2 ? 0 : cur + 1;
    nx = nx == 2 ? 0 : nx + 1;
  }
  // C/D: col = lane&15, row = quad*4 + reg  [verified m89/m91]
  #pragma unroll
  for (int mi = 0; mi < 4; ++mi) {
    int rr = r0 + wr + mi * 16 + q * 4;
    #pragma unroll
    for (int ni = 0; ni < 4; ++ni) {
      int cc = j0 + wc + ni * 16 + l15;
      #pragma unroll
      for (int rg = 0; rg < 4; ++rg)
        Y[(size_t)(rr + rg) * CB + cc] = f2bf(acc[mi][ni][rg]);
    }
  }
}

// ---------------------------------------------------------------- per-node einsum via MFMA; B-frags coalesced; ks 0..2 hoisted (T14)
template <int MODE>  // 0: sigmoid -> bf16 gate buf ; 1: tanh + GRU combine -> fp32 d_out
__global__ __launch_bounds__(256)
void k_einsum(const float* __restrict__ e, const ushort* __restrict__ Wm, const float* __restrict__ bp,
              const __hip_bfloat16* __restrict__ Y,
              const float* __restrict__ x, const float* __restrict__ state,
              const __hip_bfloat16* __restrict__ zbuf, const __hip_bfloat16* __restrict__ rbuf,
              void* __restrict__ outp) {
  constexpr int LDK = 168;
  constexpr int LDR = 72;
  __shared__ __align__(16) ushort xg[64 * LDK];
  __shared__ __align__(16) ushort res[64 * LDR];
  __shared__ float bl[64];
  const int n = blockIdx.x, t = threadIdx.x;
  const int l15 = t & 15, q = (t >> 4) & 3, w = t >> 6;
  const int wm = (w >> 1) * 32, wn = (w & 1) * 32;
  const ushort* Wn = Wm + (size_t)n * JW;
  // T14: issue the first 3 ks-planes' B-frags now; HBM latency hides under xg build.
  s8 hb0 = *(const s8*)(Wn + 0 * 2048 + (wn + l15) * 32 + q * 8);
  s8 hb1 = *(const s8*)(Wn + 0 * 2048 + (wn + 16 + l15) * 32 + q * 8);
  s8 hb2 = *(const s8*)(Wn + 1 * 2048 + (wn + l15) * 32 + q * 8);
  s8 hb3 = *(const s8*)(Wn + 1 * 2048 + (wn + 16 + l15) * 32 + q * 8);
  s8 hb4 = *(const s8*)(Wn + 2 * 2048 + (wn + l15) * 32 + q * 8);
  s8 hb5 = *(const s8*)(Wn + 2 * 2048 + (wn + 16 + l15) * 32 + q * 8);
  if (t < 64) {
    float s = 0.f;
    const float* ep = e + (size_t)n * D_;
    #pragma unroll
    for (int d = 0; d < D_; ++d) s += ep[d] * bp[d * 64 + t];   // e: L1 broadcast
    bl[t] = s;
  }
  {
    const int b = t >> 2, j = t & 3;
    const size_t bn = (size_t)b * N_ + n;
    float sv[16];
    const float* sp = state + bn * 64 + j * 16;
    #pragma unroll
    for (int i = 0; i < 16; i += 4) {
      float4 v = *(const float4*)(sp + i);
      sv[i] = v.x; sv[i + 1] = v.y; sv[i + 2] = v.z; sv[i + 3] = v.w;
    }
    if (MODE) {
      const ushort* zp = (const ushort*)zbuf + bn * 64 + j * 16;
      uint4 z0 = *(const uint4*)&zp[0], z1 = *(const uint4*)&zp[8];
      uint zw[8] = {z0.x, z0.y, z0.z, z0.w, z1.x, z1.y, z1.z, z1.w};
      #pragma unroll
      for (int i = 0; i < 8; ++i) {
        sv[2 * i]     *= bf2f((ushort)(zw[i] & 0xffffu));
        sv[2 * i + 1] *= bf2f((ushort)(zw[i] >> 16));
      }
    }
    ushort* xr = &xg[b * LDK + 2 + j * 16];
    #pragma unroll
    for (int i = 0; i < 16; i += 2) {
      uint pk = packbf(sv[i], sv[i + 1]);
      *(uint*)&xr[i] = pk;
    }
    const ushort* yp = (const ushort*)Y + (size_t)n * CB + b * C_ + j * 16;
    uint* xy = (uint*)&xg[b * LDK + 66 + j * 16];
    #pragma unroll
    for (int i = 0; i < 8; ++i) xy[i] = *(const uint*)&yp[2 * i];
    if (j == 0) *(uint*)&xg[b * LDK + 130] = *(const uint*)&yp[64];
    if (t < 64) {
      const float* xp = x + ((size_t)t * N_ + n) * DIN;
      uint pk = packbf(xp[0], xp[1]);
      *(uint*)&xg[t * LDK] = pk;
    }
    ushort* pg = &xg[b * LDK + 132 + j * 7];
    #pragma unroll
    for (int i = 0; i < 7; ++i) pg[i] = 0;
  }
  __syncthreads();
  f4 acc[2][2];
  acc[0][0] = acc[0][1] = acc[1][0] = acc[1][1] = (f4)0.0f;
  #pragma unroll
  for (int ks = 0; ks < 5; ++ks) {
    s8 af[2], bfr[2];
    #pragma unroll
    for (int mi = 0; mi < 2; ++mi) af[mi] = *(const s8*)&xg[(wm + mi * 16 + l15) * LDK + ks * 32 + q * 8];
    if (ks == 0)      { bfr[0] = hb0; bfr[1] = hb1; }
    else if (ks == 1) { bfr[0] = hb2; bfr[1] = hb3; }
    else if (ks == 2) { bfr[0] = hb4; bfr[1] = hb5; }
    else {
      bfr[0] = *(const s8*)(Wn + ks * 2048 + (wn + l15) * 32 + q * 8);
      bfr[1] = *(const s8*)(Wn + ks * 2048 + (wn + 16 + l15) * 32 + q * 8);
    }
    #pragma unroll
    for (int mi = 0; mi < 2; ++mi)
      #pragma unroll
      for (int ni = 0; ni < 2; ++ni)
        acc[mi][ni] = __builtin_amdgcn_mfma_f32_16x16x32_bf16(af[mi], bfr[ni], acc[mi][ni], 0, 0, 0);
  }
  {
    float bl0 = bl[wn + l15], bl1 = bl[wn + 16 + l15];
    #pragma unroll
    for (int mi = 0; mi < 2; ++mi)
      #pragma unroll
      for (int ni = 0; ni < 2; ++ni) {
        float bb = ni ? bl1 : bl0;
        #pragma unroll
        for (int rg = 0; rg < 4; ++rg) {
          float v = acc[mi][ni][rg] + bb;
          float a;
          if (MODE == 0) a = 1.0f / (1.0f + __expf(-v));
          else           a = 1.0f - 2.0f / (__expf(2.0f * v) + 1.0f);
          res[(wm + mi * 16 + q * 4 + rg) * LDR + (wn + ni * 16 + l15)] = f2bf(a);
        }
      }
  }
  __syncthreads();
  {
    const int b = t >> 2, j = t & 3;
    const size_t gb = ((size_t)b * N_ + n) * 64 + j * 16;
    const ushort* rr = &res[b * LDR + j * 16];
    if (MODE == 0) {
      uint4 v0 = *(const uint4*)&rr[0];
      uint4 v1 = *(const uint4*)&rr[8];
      *(uint4*)((ushort*)outp + gb) = v0;
      *(uint4*)((ushort*)outp + gb + 8) = v1;
    } else {
      float* ob = (float*)outp;
      const float* stp = state + gb;
      const ushort* rp = (const ushort*)rbuf + gb;
      uint4 r0 = *(const uint4*)&rp[0], r1 = *(const uint4*)&rp[8];
      uint rw[8] = {r0.x, r0.y, r0.z, r0.w, r1.x, r1.y, r1.z, r1.w};
      #pragma unroll
      for (int i = 0; i < 16; i += 4) {
        float4 st = *(const float4*)(stp + i);
        float4 ov;
        float rv0 = bf2f((ushort)(rw[i / 2] & 0xffffu));
        float rv1 = bf2f((ushort)(rw[i / 2] >> 16));
        float rv2 = bf2f((ushort)(rw[i / 2 + 1] & 0xffffu));
        float rv3 = bf2f((ushort)(rw[i / 2 + 1] >> 16));
        ov.x = rv0 * st.x + (1.0f - rv0) * bf2f(rr[i]);
        ov.y = rv1 * st.y + (1.0f - rv1) * bf2f(rr[i + 1]);
        ov.z = rv2 * st.z + (1.0f - rv2) * bf2f(rr[i + 2]);
        ov.w = rv3 * st.w + (1.0f - rv3) * bf2f(rr[i + 3]);
        *(float4*)(ob + gb + i) = ov;
      }
    }
  }
}

// ----------------------------------------------------------------
extern "C" void kernel_launch(void* const* d_in, const int* in_sizes, int n_in,
                              void* d_out, int out_size, void* d_ws, size_t ws_size,
                              hipStream_t stream) {
  const float* x     = (const float*)d_in[0];
  const float* state = (const float*)d_in[1];
  const float* node  = (const float*)d_in[2];
  const float* timee = (const float*)d_in[3];
  const float* W_z = (const float*)d_in[4];
  const float* b_z = (const float*)d_in[5];
  const float* g_z = (const float*)d_in[6];
  const float* be_z = (const float*)d_in[7];
  const float* W_r = (const float*)d_in[8];
  const float* b_r = (const float*)d_in[9];
  const float* g_r = (const float*)d_in[10];
  const float* be_r = (const float*)d_in[11];
  const float* W_u = (const float*)d_in[12];
  const float* b_u = (const float*)d_in[13];
  const float* g_u = (const float*)d_in[14];
  const float* be_u = (const float*)d_in[15];

  constexpr size_t NN = (size_t)N_ * N_;
  constexpr size_t ND = (size_t)N_ * D_;
  char* ws = (char*)d_ws;
  float*           e  = (float*)(ws);                        //       0 :    393,216
  __hip_bfloat16*  A  = (__hip_bfloat16*)(ws + 393216);      //  25,165,824
  __hip_bfloat16*  XT = (__hip_bfloat16*)(ws + 25559040);    //  17,301,504
  __hip_bfloat16*  Y  = (__hip_bfloat16*)(ws + 42860544);    //  17,301,504
  __hip_bfloat16*  zb = (__hip_bfloat16*)(ws + 60162048);    //  16,777,216
  __hip_bfloat16*  rb = (__hip_bfloat16*)(ws + 76939264);    //  16,777,216
  ushort*          ebf = (ushort*)(ws + 93716480);           //  196,608 (dead before Wm written)
  ushort*          Wm = (ushort*)(ws + 93716480);            //  41,943,040 (ends 135,659,520)
  __hip_bfloat16*  Yr = (__hip_bfloat16*)(ws + 135659520);   //  17,301,504 (big-ws only)
  const size_t YRD = ((size_t)135659520 - 42860544) / 2;
  const bool big = ws_size >= (size_t)152961024;
  // Wpb scratch (327,680 B) in provably-dead windows:
  //  z: zb base (einsum z writes zb AFTER wmat3 z consumed Wpb_z)
  //  r: rb base (einsum r writes rb AFTER wmat3 r consumed Wpb_r)
  //  u: A_z panel base (dead after the z(+r) GEMM; wcvt u runs after gemm z+r)
  ushort* Wpb_z = (ushort*)(ws + 60162048);
  ushort* Wpb_r = (ushort*)(ws + 76939264);
  ushort* Wpb_u = (ushort*)(ws + 393216);

  float* out = (float*)d_out;

  dim3 ggrid1(CB / 128, N_ / 128, 1);   // 528 blocks (%8==0)
  dim3 ggrid2(CB / 128, N_ / 128, 2);   // fused z+r: 1056 blocks (%8==0)
  dim3 wgrid3(N_ / 16, 8);              // k_wmat3: 1024 blocks

  if (big) {
    // 10-dispatch schedule
    k_fuse1<<<88, 256, 0, stream>>>(node, timee, g_z, be_z, g_r, be_r, g_u, be_u,
                                    e, ebf, W_z, Wpb_z, W_r, Wpb_r);
    k_attn<<<dim3(N_ / 16, 1, 3), 256, 0, stream>>>(ebf, A);
    k_fuse3<<<3072, 256, 0, stream>>>(x, state, XT, e + 0 * ND, Wpb_z, Wm);
    k_gemm<<<ggrid2, 256, 0, stream>>>(A, NN, XT, Y, YRD);                       // z->Y, r->Yr
    k_einsum<0><<<N_, 256, 0, stream>>>(e + 0 * ND, Wm, b_z, Y, x, state, nullptr, nullptr, (void*)zb);
    k_fuse6<<<3112, 256, 0, stream>>>(x, state, zb, XT, e + 1 * ND, Wpb_r, Wm, W_u, Wpb_u);
    k_einsum<0><<<N_, 256, 0, stream>>>(e + 1 * ND, Wm, b_r, Yr, x, state, nullptr, nullptr, (void*)rb);
    k_wmat3<<<wgrid3, 256, 0, stream>>>(e + 2 * ND, Wpb_u, Wm);
    k_gemm<<<ggrid1, 256, 0, stream>>>(A + 2 * NN, 0, XT, Y, 0);
    k_einsum<1><<<N_, 256, 0, stream>>>(e + 2 * ND, Wm, b_u, Y, x, state, zb, rb, (void*)out);
  } else {
    // small-ws fallback: original ordering (XT reused between gemms)
    k_fuse1<<<88, 256, 0, stream>>>(node, timee, g_z, be_z, g_r, be_r, g_u, be_u,
                                    e, ebf, W_z, Wpb_z, W_r, Wpb_r);
    k_attn<<<dim3(N_ / 16, 1, 3), 256, 0, stream>>>(ebf, A);
    k_fuse3<<<3072, 256, 0, stream>>>(x, state, XT, e + 0 * ND, Wpb_z, Wm);
    k_gemm<<<ggrid1, 256, 0, stream>>>(A, 0, XT, Y, 0);
    k_einsum<0><<<N_, 256, 0, stream>>>(e + 0 * ND, Wm, b_z, Y, x, state, nullptr, nullptr, (void*)zb);
    k_wmat3<<<wgrid3, 256, 0, stream>>>(e + 1 * ND, Wpb_r, Wm);
    k_gemm<<<ggrid1, 256, 0, stream>>>(A + NN, 0, XT, Y, 0);
    k_einsum<0><<<N_, 256, 0, stream>>>(e + 1 * ND, Wm, b_r, Y, x, state, nullptr, nullptr, (void*)rb);
    k_buildX<1><<<dim3(32, 64), 256, 0, stream>>>(x, state, zb, XT);
    k_wcvt1<<<40, 256, 0, stream>>>(W_u, Wpb_u);
    k_wmat3<<<wgrid3, 256, 0, stream>>>(e + 2 * ND, Wpb_u, Wm);
    k_gemm<<<ggrid1, 256, 0, stream>>>(A + 2 * NN, 0, XT, Y, 0);
    k_einsum<1><<<N_, 256, 0, stream>>>(e + 2 * ND, Wm, b_u, Y, x, state, zb, rb, (void*)out);
  }
}